// Round 19
// baseline (2616.874 us; speedup 1.0000x reference)
//
#include <hip/hip_runtime.h>

typedef _Float16 f16;
typedef _Float16 f16x2 __attribute__((ext_vector_type(2)));
typedef _Float16 f16x4 __attribute__((ext_vector_type(4)));
typedef _Float16 f16x8 __attribute__((ext_vector_type(8)));
typedef float f32x4 __attribute__((ext_vector_type(4)));

#define NN 100000
#define NE 160000
#define NB 4096
#define HD 512

// ---- workspace layout (WS_NEEDED = 146,477,712 B < 160 MiB) ----
#define O_H8    0UL
#define O_SCE   81920000UL
#define O_SHR   87040000UL
#define O_WT    141440000UL
#define O_OFF   145437696UL
#define O_EID   145837712UL
#define WS_NEEDED 146477712UL
#define V_POOL  0UL
#define V_PH    8388608UL
#define V_T1    12582912UL
#define V_CNT   16777216UL
#define V_FILL  17177232UL
#define V_BSUM  17577248UL

__global__ void zero16(ulong2* __restrict__ p, long n) {
  long i = (long)blockIdx.x * 256 + threadIdx.x;
  if (i < n) p[i] = ulong2{0UL, 0UL};
}
__global__ void diag(float* __restrict__ out, int n, float v) {
  int i = blockIdx.x * 256 + threadIdx.x;
  if (i < n) out[i] = v;
}

__global__ void transcast(const float* __restrict__ src, f16* __restrict__ dst,
                          int Kreal, int Kpad) {
  int id = blockIdx.x * 256 + threadIdx.x;
  if (id >= 512 * Kpad) return;
  int n = id / Kpad, k = id % Kpad;
  dst[((k >> 5) * 512 + n) * 32 + (k & 31)] =
      (k < Kreal) ? (f16)src[(size_t)k * 512 + n] : (f16)0.f;
}

// ---------------- CSR by col ----------------
__global__ void countK(const int* __restrict__ col, int* __restrict__ cnt) {
  int e = blockIdx.x * 256 + threadIdx.x;
  if (e < NE) atomicAdd(&cnt[col[e]], 1);
}
__global__ __launch_bounds__(1024) void scanA(const int* __restrict__ cnt,
                                              int* __restrict__ incl, int* __restrict__ bsum) {
  __shared__ int s[1024];
  int i = blockIdx.x * 1024 + threadIdx.x;
  s[threadIdx.x] = (i < NN) ? cnt[i] : 0;
  __syncthreads();
  for (int d = 1; d < 1024; d <<= 1) {
    int t = (threadIdx.x >= d) ? s[threadIdx.x - d] : 0;
    __syncthreads();
    s[threadIdx.x] += t;
    __syncthreads();
  }
  if (i < NN) incl[i] = s[threadIdx.x];
  if (threadIdx.x == 1023) bsum[blockIdx.x] = s[1023];
}
__global__ void scanB(int* bsum, int nb) {
  if (threadIdx.x == 0 && blockIdx.x == 0) {
    int run = 0;
    for (int i = 0; i < nb; ++i) { int t = bsum[i]; bsum[i] = run; run += t; }
  }
}
__global__ __launch_bounds__(1024) void scanC(const int* __restrict__ cnt,
                                              int* __restrict__ incl_fill,
                                              const int* __restrict__ bsum,
                                              int* __restrict__ off) {
  int i = blockIdx.x * 1024 + threadIdx.x;
  if (i >= NN) return;
  int g = incl_fill[i] + bsum[blockIdx.x];
  off[i + 1] = g;
  incl_fill[i] = g - cnt[i];
  if (i == 0) off[0] = 0;
}
__global__ void scatterK(const int* __restrict__ col, int* __restrict__ fill,
                         int* __restrict__ eid) {
  int e = blockIdx.x * 256 + threadIdx.x;
  if (e >= NE) return;
  int p = atomicAdd(&fill[col[e]], 1);
  eid[p] = e;
}

// ---------------- msgk<C0>: leave-one-out message; single CSR walk with
// register cache for the first 8 edges (avg degree 1.6 -> ~all nodes).
template<int C0>
__global__ __launch_bounds__(256, 4)
void msgk(const char* __restrict__ z8, const float* __restrict__ sce,
          const int* __restrict__ off, const int* __restrict__ eid,
          char* __restrict__ msgq, float* __restrict__ scm) {
  int tid = threadIdx.x, wid = tid >> 6, lane = tid & 63;
  int n = blockIdx.x * 4 + wid;
  int s0 = off[n], s1 = off[n + 1];
  int cnt = s1 - s0;
  int g = lane >> 4;
  float a[4] = {0.f, 0.f, 0.f, 0.f};
  int ec[8]; unsigned uc[8]; float scc[8];
  #pragma unroll
  for (int i = 0; i < 8; ++i) {
    if (i < cnt) {
      int e = eid[s0 + i];
      ec[i] = e;
      scc[i] = sce[e * 8 + (C0 >> 6) + g];
      uc[i] = *reinterpret_cast<const unsigned*>(z8 + (size_t)e * 512 + C0 + lane * 4);
      #pragma unroll
      for (int b = 0; b < 4; ++b)
        a[b] += (float)(char)((uc[i] >> (8 * b)) & 0xff) * scc[i];
    }
  }
  for (int p = s0 + 8; p < s1; ++p) {
    int e = eid[p];
    float sc = sce[e * 8 + (C0 >> 6) + g];
    unsigned u = *reinterpret_cast<const unsigned*>(z8 + (size_t)e * 512 + C0 + lane * 4);
    #pragma unroll
    for (int b = 0; b < 4; ++b)
      a[b] += (float)(char)((u >> (8 * b)) & 0xff) * sc;
  }
  #pragma unroll
  for (int i = 0; i < 8; ++i) {
    if (i < cnt) {
      int f = ec[i] ^ 1;
      float mv[4]; float m = 0.f;
      #pragma unroll
      for (int b = 0; b < 4; ++b) {
        mv[b] = a[b] - (float)(char)((uc[i] >> (8 * b)) & 0xff) * scc[i];
        m = fmaxf(m, fabsf(mv[b]));
      }
      #pragma unroll
      for (int d = 1; d < 16; d <<= 1) m = fmaxf(m, __shfl_xor(m, d));
      float s2 = (m > 0.f) ? m / 127.f : 1.f;
      if ((lane & 15) == 0) scm[f * 4 + g] = s2;
      unsigned q = 0;
      #pragma unroll
      for (int b = 0; b < 4; ++b) {
        int qi = __float2int_rn(mv[b] / s2);
        qi = min(127, max(-127, qi));
        q |= ((unsigned)(unsigned char)(char)qi) << (8 * b);
      }
      *reinterpret_cast<unsigned*>(msgq + (size_t)f * 256 + lane * 4) = q;
    }
  }
  for (int p = s0 + 8; p < s1; ++p) {
    int e = eid[p];
    int f = e ^ 1;
    float sc = sce[e * 8 + (C0 >> 6) + g];
    unsigned u = *reinterpret_cast<const unsigned*>(z8 + (size_t)e * 512 + C0 + lane * 4);
    float mv[4]; float m = 0.f;
    #pragma unroll
    for (int b = 0; b < 4; ++b) {
      mv[b] = a[b] - (float)(char)((u >> (8 * b)) & 0xff) * sc;
      m = fmaxf(m, fabsf(mv[b]));
    }
    #pragma unroll
    for (int d = 1; d < 16; d <<= 1) m = fmaxf(m, __shfl_xor(m, d));
    float s2 = (m > 0.f) ? m / 127.f : 1.f;
    if ((lane & 15) == 0) scm[f * 4 + g] = s2;
    unsigned q = 0;
    #pragma unroll
    for (int b = 0; b < 4; ++b) {
      int qi = __float2int_rn(mv[b] / s2);
      qi = min(127, max(-127, qi));
      q |= ((unsigned)(unsigned char)(char)qi) << (8 * b);
    }
    *reinterpret_cast<unsigned*>(msgq + (size_t)f * 256 + lane * 4) = q;
  }
}

// ---------------- tker: s_node = segsum(h,col) ----------------
__global__ __launch_bounds__(256, 4)
void tker(const char* __restrict__ h8, const float* __restrict__ sce,
          const int* __restrict__ off, const int* __restrict__ eid,
          char* __restrict__ nb8, float* __restrict__ scn) {
  int tid = threadIdx.x, wid = tid >> 6, lane = tid & 63;
  int n = blockIdx.x * 4 + wid;
  int s0 = off[n], s1 = off[n + 1];
  int g = lane >> 3;
  float a[8] = {0.f,0.f,0.f,0.f,0.f,0.f,0.f,0.f};
  for (int p = s0; p < s1; ++p) {
    int e = eid[p];
    float sc = sce[e * 8 + g];
    uint2 u = *reinterpret_cast<const uint2*>(h8 + (size_t)e * 512 + lane * 8);
    #pragma unroll
    for (int b = 0; b < 4; ++b) {
      a[b]     += (float)((u.x >> (8 * b)) & 0xff) * sc;
      a[4 + b] += (float)((u.y >> (8 * b)) & 0xff) * sc;
    }
  }
  float m = 0.f;
  #pragma unroll
  for (int j = 0; j < 8; ++j) m = fmaxf(m, a[j]);
  #pragma unroll
  for (int d = 1; d < 8; d <<= 1) m = fmaxf(m, __shfl_xor(m, d));
  float s2 = (m > 0.f) ? m / 255.f : 1.f;
  if ((lane & 7) == 0) scn[n * 8 + g] = s2;
  unsigned lo = 0, hi = 0;
  #pragma unroll
  for (int b = 0; b < 4; ++b) {
    int q0 = __float2int_rn(a[b] / s2);     q0 = min(255, max(0, q0));
    int q1 = __float2int_rn(a[4 + b] / s2); q1 = min(255, max(0, q1));
    lo |= ((unsigned)q0) << (8 * b);
    hi |= ((unsigned)q1) << (8 * b);
  }
  *reinterpret_cast<uint2*>(nb8 + (size_t)n * 512 + lane * 8) = uint2{lo, hi};
}

// ---------------- shared GEMM helpers ----------------
static __device__ __forceinline__ void stageB512(const f16* __restrict__ wsrc,
                                                 f16* __restrict__ Bs, int tid) {
  #pragma unroll
  for (int j = 0; j < 4; ++j) {
    int u = tid * 4 + j;
    *reinterpret_cast<f16x8*>(&Bs[(u >> 2) * 40 + (u & 3) * 8]) =
        *reinterpret_cast<const f16x8*>(&wsrc[u * 8]);
  }
}
template<int AS>
static __device__ __forceinline__ void mstep8(const f16* __restrict__ As,
                                              const f16* __restrict__ Bs,
                                              f32x4 acc[2][8], int wm, int wn,
                                              int fr, int fg, int ko) {
  f16x8 af[2];
  #pragma unroll
  for (int mf = 0; mf < 2; ++mf)
    af[mf] = *reinterpret_cast<const f16x8*>(&As[(wm + mf * 16 + fr) * AS + ko + fg * 8]);
  #pragma unroll
  for (int nf = 0; nf < 8; ++nf) {
    f16x8 bf = *reinterpret_cast<const f16x8*>(&Bs[(wn + nf * 16 + fr) * 40 + fg * 8]);
    #pragma unroll
    for (int mf = 0; mf < 2; ++mf)
      acc[mf][nf] = __builtin_amdgcn_mfma_f32_16x16x32_f16(af[mf], bf, acc[mf][nf], 0, 0, 0);
  }
}

// B fragments straight from global (L2-hot weights) — used by e2n.
static __device__ __forceinline__ void loadBfrag(const f16* __restrict__ wp,
                                                 f16x8 bf[8], int wn, int fr, int fg) {
  #pragma unroll
  for (int nf = 0; nf < 8; ++nf)
    bf[nf] = *reinterpret_cast<const f16x8*>(&wp[(size_t)(wn + nf * 16 + fr) * 32 + fg * 8]);
}

static __device__ __forceinline__ f16x2 pkfma(f16x2 a, f16x2 b, f16x2 c) {
  f16x2 r;
  asm("v_pk_fma_f16 %0, %1, %2, %3" : "=v"(r) : "v"(a), "v"(b), "v"(c));
  return r;
}

// vectorized x-row stage: 4x dwordx4 + scalar tail, write f16x4 to LDS row
static __device__ __forceinline__ void stageXrow(const float* __restrict__ xr,
                                                 f16* __restrict__ dstRow, int s) {
  #pragma unroll
  for (int j = 0; j < 4; ++j) {
    float v[4];
    __builtin_memcpy(v, xr + 4 * s + 32 * j, 16);
    f16 t4[4];
    #pragma unroll
    for (int b = 0; b < 4; ++b) t4[b] = (f16)v[b];
    *reinterpret_cast<f16x4*>(&dstRow[4 * s + 32 * j]) = *reinterpret_cast<f16x4*>(t4);
  }
  if (s < 5) dstRow[128 + s] = (f16)xr[128 + s];
}

// ---------------- zk: z = h @ W. Barrier-free K-loop: 256 threads / 32-edge
// tile; each of 4 waves owns a private 128-col B slice in LDS (no sharing ->
// no per-step barriers; LDS ops within a wave complete in order).
// LDS = Af 16.9K + Bw 40K = 56.9K -> 2 blocks/CU. Numerics identical.
__global__ __launch_bounds__(256, 2)
void zk(char* __restrict__ h8, float* __restrict__ sce, const f16* __restrict__ wst) {
  __shared__ f16 Af[32 * 264];        // half-K (256) f16 A tile
  __shared__ f16 Bw[4][128 * 40];     // per-wave B slice (128 cols x 32 halves, pad 40)
  const int tid = threadIdx.x, lane = tid & 63, wid = tid >> 6;  // 4 waves
  const int fr = lane & 15, fg = lane >> 4;
  const int wn = wid * 128;
  const int e0 = blockIdx.x * 32;
  const int sr = tid >> 3;            // staging row 0..31
  const int sc8 = tid & 7;            // staging chunk (32 u8) within half

  auto stageA = [&](int phase) {
    const int kb = phase * 256 + sc8 * 32;
    float sa = sce[(size_t)(e0 + sr) * 8 + (kb >> 6)];
    const f16 sh = (f16)sa;
    const f16 bh = (f16)(-1024.f * sa);
    f16x2 s2; s2[0] = sh; s2[1] = sh;
    f16x2 b2; b2[0] = bh; b2[1] = bh;
    const int4* src = reinterpret_cast<const int4*>(h8 + (size_t)(e0 + sr) * 512 + kb);
    f16* dst = &Af[sr * 264 + sc8 * 32];
    #pragma unroll
    for (int j = 0; j < 2; ++j) {
      int4 w = src[j];
      unsigned vv[4] = {(unsigned)w.x, (unsigned)w.y, (unsigned)w.z, (unsigned)w.w};
      #pragma unroll
      for (int q = 0; q < 2; ++q) {
        unsigned p0 = __builtin_amdgcn_perm(0x64646464u, vv[2*q],     0x05010400u);
        unsigned p1 = __builtin_amdgcn_perm(0x64646464u, vv[2*q],     0x05030402u);
        unsigned p2 = __builtin_amdgcn_perm(0x64646464u, vv[2*q + 1], 0x05010400u);
        unsigned p3 = __builtin_amdgcn_perm(0x64646464u, vv[2*q + 1], 0x05030402u);
        uint4 o;
        o.x = __builtin_bit_cast(unsigned, pkfma(__builtin_bit_cast(f16x2, p0), s2, b2));
        o.y = __builtin_bit_cast(unsigned, pkfma(__builtin_bit_cast(f16x2, p1), s2, b2));
        o.z = __builtin_bit_cast(unsigned, pkfma(__builtin_bit_cast(f16x2, p2), s2, b2));
        o.w = __builtin_bit_cast(unsigned, pkfma(__builtin_bit_cast(f16x2, p3), s2, b2));
        *reinterpret_cast<uint4*>(dst + j * 16 + q * 8) = o;
      }
    }
  };

  // wave-private B stage of step s: global (contiguous 8KB slice) -> own LDS
  auto stageBw = [&](int s, f16x8* pf) {
    const f16* wsrc = wst + (size_t)s * 16384 + (size_t)wn * 32;
    #pragma unroll
    for (int j = 0; j < 8; ++j)
      pf[j] = *reinterpret_cast<const f16x8*>(&wsrc[(size_t)(j * 64 + lane) * 8]);
  };
  auto writeBw = [&](f16x8* pf) {
    #pragma unroll
    for (int j = 0; j < 8; ++j) {
      int u = j * 64 + lane;
      *reinterpret_cast<f16x8*>(&Bw[wid][(u >> 2) * 40 + (u & 3) * 8]) = pf[j];
    }
  };

  stageA(0);
  { f16x8 p0[8]; stageBw(0, p0); writeBw(p0); }
  __syncthreads();
  f32x4 acc[2][8] = {};
  for (int step = 0; step < 16; ++step) {
    if (step == 8) { __syncthreads(); stageA(1); __syncthreads(); }
    f16x8 pf[8];
    if (step < 15) stageBw(step + 1, pf);   // global loads in flight during MFMA
    const int ko = (step & 7) * 32;
    f16x8 af[2];
    #pragma unroll
    for (int mf = 0; mf < 2; ++mf)
      af[mf] = *reinterpret_cast<const f16x8*>(&Af[(mf * 16 + fr) * 264 + ko + fg * 8]);
    f16x8 bf[8];
    #pragma unroll
    for (int nf = 0; nf < 8; ++nf)
      bf[nf] = *reinterpret_cast<const f16x8*>(&Bw[wid][(nf * 16 + fr) * 40 + fg * 8]);
    #pragma unroll
    for (int nf = 0; nf < 8; ++nf)
      #pragma unroll
      for (int mf = 0; mf < 2; ++mf)
        acc[mf][nf] = __builtin_amdgcn_mfma_f32_16x16x32_f16(af[mf], bf[nf], acc[mf][nf], 0, 0, 0);
    if (step < 15) writeBw(pf);             // own-slice overwrite: in-order LDS, no barrier
  }
  __syncthreads();   // all waves done with Bw before bounce reuse
  // epilogue: per (row, group64) scales
  float scA[2][4], scB[2][4];
  #pragma unroll
  for (int mf = 0; mf < 2; ++mf)
    #pragma unroll
    for (int i = 0; i < 4; ++i) {
      float mA = 0.f, mB = 0.f;
      #pragma unroll
      for (int nf = 0; nf < 4; ++nf) mA = fmaxf(mA, fabsf(acc[mf][nf][i]));
      #pragma unroll
      for (int nf = 4; nf < 8; ++nf) mB = fmaxf(mB, fabsf(acc[mf][nf][i]));
      #pragma unroll
      for (int d = 1; d < 16; d <<= 1) {
        mA = fmaxf(mA, __shfl_xor(mA, d));
        mB = fmaxf(mB, __shfl_xor(mB, d));
      }
      scA[mf][i] = (mA > 0.f) ? mA / 127.f : 1.f;
      scB[mf][i] = (mB > 0.f) ? mB / 127.f : 1.f;
      if (fr == 0) {
        int r = mf * 16 + fg * 4 + i;
        sce[(size_t)(e0 + r) * 8 + (wn >> 6)]     = scA[mf][i];
        sce[(size_t)(e0 + r) * 8 + (wn >> 6) + 1] = scB[mf][i];
      }
    }
  char* q8 = (char*)&Bw[0][0];   // bounce: 32 rows x 512 = 16KB (fits in Bw)
  #pragma unroll
  for (int mf = 0; mf < 2; ++mf)
    #pragma unroll
    for (int nf = 0; nf < 8; ++nf) {
      int c = wn + nf * 16 + fr;
      #pragma unroll
      for (int i = 0; i < 4; ++i) {
        int r = mf * 16 + fg * 4 + i;
        float s = (nf < 4) ? scA[mf][i] : scB[mf][i];
        int q = __float2int_rn(acc[mf][nf][i] / s);
        q8[r * 512 + c] = (char)min(127, max(-127, q));
      }
    }
  __syncthreads();
  { int r = tid >> 3, kb = (tid & 7) * 64;
    int4* dst = reinterpret_cast<int4*>(h8 + (size_t)(e0 + r) * 512 + kb);
    const int4* s4 = reinterpret_cast<const int4*>(&q8[r * 512 + kb]);
    #pragma unroll
    for (int j = 0; j < 4; ++j) dst[j] = s4[j]; }
}

// ---------------- convup: half-width, double-buffered B; vectorized gather ----------------
template<int MODE>
__global__ __launch_bounds__(512, 2)
void convup(const float* __restrict__ x, const float* __restrict__ ea,
            const int* __restrict__ row, const f16* __restrict__ wi,
            const float* __restrict__ bi, const float* __restrict__ bc,
            char* __restrict__ h8, float* __restrict__ sce,
            const char* __restrict__ msgq, const float* __restrict__ scm,
            int c0) {
  __shared__ f16 As[64 * 168];
  __shared__ f16 Bs[2][256 * 40];
  __shared__ char m8s[64 * 256];
  __shared__ float scmL[64 * 4];
  const int tid = threadIdx.x, lane = tid & 63, wid = tid >> 6;
  const int fr = lane & 15, fg = lane >> 4;
  const int wm = (wid >> 2) * 32, wn = (wid & 3) * 64;
  const int e0 = blockIdx.x * 64;

  { // stage A1 = [x[row]|ea] pad->160 (vectorized); msg tile for MODE 1
    int r = tid >> 3, s = tid & 7;
    int rid = row[e0 + r];
    stageXrow(x + (size_t)rid * 133, &As[r * 168], s);
    if (s < 7) {
      float2 e2 = *reinterpret_cast<const float2*>(ea + (size_t)(e0 + r) * 14 + 2 * s);
      As[r * 168 + 133 + 2 * s]     = (f16)e2.x;
      As[r * 168 + 133 + 2 * s + 1] = (f16)e2.y;
    }
    for (int k = 147 + s; k < 160; k += 8) As[r * 168 + k] = (f16)0.f;
    if (MODE == 1) {
      const int4* ms = reinterpret_cast<const int4*>(msgq + (size_t)(e0 + r) * 256 + s * 32);
      int4* md = reinterpret_cast<int4*>(m8s + r * 256 + s * 32);
      md[0] = ms[0]; md[1] = ms[1];
      if (s < 4) scmL[r * 4 + s] = scm[(size_t)(e0 + r) * 4 + s];
    }
  }
  { // prologue: stage B step 0
    #pragma unroll
    for (int j = 0; j < 2; ++j) {
      int u = tid * 2 + j;
      *reinterpret_cast<f16x8*>(&Bs[0][(u >> 2) * 40 + (u & 3) * 8]) =
          *reinterpret_cast<const f16x8*>(&wi[(size_t)c0 * 32 + (size_t)u * 8]);
    }
  }
  __syncthreads();
  f32x4 acc[2][4] = {};
  for (int step = 0; step < 5; ++step) {
    const int cur = step & 1;
    f16x8 pf[2];
    if (step < 4) {
      const f16* wsrc = wi + (size_t)(step + 1) * 16384 + (size_t)c0 * 32;
      #pragma unroll
      for (int j = 0; j < 2; ++j)
        pf[j] = *reinterpret_cast<const f16x8*>(&wsrc[(size_t)(tid * 2 + j) * 8]);
    }
    f16x8 af[2];
    #pragma unroll
    for (int mf = 0; mf < 2; ++mf)
      af[mf] = *reinterpret_cast<const f16x8*>(&As[(wm + mf * 16 + fr) * 168 + step * 32 + fg * 8]);
    #pragma unroll
    for (int nf = 0; nf < 4; ++nf) {
      f16x8 bf = *reinterpret_cast<const f16x8*>(&Bs[cur][(wn + nf * 16 + fr) * 40 + fg * 8]);
      #pragma unroll
      for (int mf = 0; mf < 2; ++mf)
        acc[mf][nf] = __builtin_amdgcn_mfma_f32_16x16x32_f16(af[mf], bf, acc[mf][nf], 0, 0, 0);
    }
    if (step < 4) {
      #pragma unroll
      for (int j = 0; j < 2; ++j) {
        int u = tid * 2 + j;
        *reinterpret_cast<f16x8*>(&Bs[cur ^ 1][(u >> 2) * 40 + (u & 3) * 8]) = pf[j];
      }
    }
    __syncthreads();
  }
  // epilogue: h0 = relu(gemm+bi); MODE1: h' = relu(h0 + bc + msg)
  #pragma unroll
  for (int nf = 0; nf < 4; ++nf) {
    int cl = wn + nf * 16 + fr;
    int cg = c0 + cl;
    float bi_ = bi[cg];
    float bc_ = (MODE == 1) ? bc[cg] : 0.f;
    #pragma unroll
    for (int mf = 0; mf < 2; ++mf)
      #pragma unroll
      for (int i = 0; i < 4; ++i) {
        int r = wm + mf * 16 + fg * 4 + i;
        float v = fmaxf(acc[mf][nf][i] + bi_, 0.f);
        if (MODE == 1) {
          float mv = (float)(char)m8s[r * 256 + cl] * scmL[r * 4 + (cl >> 6)];
          v = fmaxf(v + bc_ + mv, 0.f);
        }
        acc[mf][nf][i] = v;
      }
  }
  float sc_[2][4];
  #pragma unroll
  for (int mf = 0; mf < 2; ++mf)
    #pragma unroll
    for (int i = 0; i < 4; ++i) {
      float m = 0.f;
      #pragma unroll
      for (int nf = 0; nf < 4; ++nf) m = fmaxf(m, acc[mf][nf][i]);
      #pragma unroll
      for (int d = 1; d < 16; d <<= 1) m = fmaxf(m, __shfl_xor(m, d));
      sc_[mf][i] = (m > 0.f) ? m / 255.f : 1.f;
      if (fr == 0)
        sce[(size_t)(e0 + wm + mf * 16 + fg * 4 + i) * 8 + (c0 >> 6) + (wn >> 6)] = sc_[mf][i];
    }
  __syncthreads();
  #pragma unroll
  for (int mf = 0; mf < 2; ++mf)
    #pragma unroll
    for (int nf = 0; nf < 4; ++nf) {
      int cl = wn + nf * 16 + fr;
      #pragma unroll
      for (int i = 0; i < 4; ++i) {
        int r = wm + mf * 16 + fg * 4 + i;
        int q = __float2int_rn(acc[mf][nf][i] / sc_[mf][i]);
        m8s[r * 256 + cl] = (char)(unsigned char)min(255, max(0, q));
      }
    }
  __syncthreads();
  { int r = tid >> 3, s = tid & 7;
    int4* dst = reinterpret_cast<int4*>(h8 + (size_t)(e0 + r) * 512 + c0 + s * 32);
    const int4* sp = reinterpret_cast<const int4*>(m8s + r * 256 + s * 32);
    dst[0] = sp[0]; dst[1] = sp[1]; }
}

// ---------------- e2n: B direct from L2, barrier-free GEMMs; vectorized gather ----------------
__global__ __launch_bounds__(512, 4)
void e2n(const float* __restrict__ x, const char* __restrict__ nb8,
         const float* __restrict__ scn, const f16* __restrict__ wex,
         const f16* __restrict__ wes, const float* __restrict__ be,
         const int* __restrict__ batch, float* __restrict__ pooled) {
  __shared__ f16 As[64 * 520];
  __shared__ int bat[64];
  const int tid = threadIdx.x, lane = tid & 63, wid = tid >> 6;
  const int fr = lane & 15, fg = lane >> 4;
  const int wm = (wid >> 2) * 32, wn = (wid & 3) * 128;
  const int n0 = blockIdx.x * 64;
  if (tid < 64) { int nn = n0 + tid; bat[tid] = (nn < NN) ? batch[nn] : 0; }
  { // x part, stride 168 (vectorized)
    int r = tid >> 3, s = tid & 7;
    int nid = min(n0 + r, NN - 1);
    stageXrow(x + (size_t)nid * 133, &As[r * 168], s);
    for (int k = 133 + s; k < 160; k += 8) As[r * 168 + k] = (f16)0.f;
  }
  __syncthreads();
  f32x4 acc[2][8] = {};
  for (int step = 0; step < 5; ++step) {
    f16x8 bf[8];
    loadBfrag(wex + (size_t)step * 16384, bf, wn, fr, fg);
    f16x8 af[2];
    #pragma unroll
    for (int mf = 0; mf < 2; ++mf)
      af[mf] = *reinterpret_cast<const f16x8*>(&As[(wm + mf * 16 + fr) * 168 + step * 32 + fg * 8]);
    #pragma unroll
    for (int nf = 0; nf < 8; ++nf)
      #pragma unroll
      for (int mf = 0; mf < 2; ++mf)
        acc[mf][nf] = __builtin_amdgcn_mfma_f32_16x16x32_f16(af[mf], bf[nf], acc[mf][nf], 0, 0, 0);
  }
  __syncthreads();
  { // re-stage As with dequantized s_node (u8 groupwise), stride 520
    int r = tid >> 3, s = tid & 7, kb = s * 64;
    int nid = min(n0 + r, NN - 1);
    float sc = scn[(size_t)nid * 8 + s];
    const int4* src = reinterpret_cast<const int4*>(nb8 + (size_t)nid * 512 + kb);
    #pragma unroll
    for (int j = 0; j < 4; ++j) {
      int4 w = src[j];
      unsigned vv[4] = {(unsigned)w.x, (unsigned)w.y, (unsigned)w.z, (unsigned)w.w};
      f16 tmp[16];
      #pragma unroll
      for (int q = 0; q < 4; ++q)
        #pragma unroll
        for (int b = 0; b < 4; ++b)
          tmp[q * 4 + b] = (f16)((float)((vv[q] >> (8 * b)) & 0xff) * sc);
      *reinterpret_cast<f16x8*>(&As[r * 520 + kb + j * 16])     = *reinterpret_cast<f16x8*>(&tmp[0]);
      *reinterpret_cast<f16x8*>(&As[r * 520 + kb + j * 16 + 8]) = *reinterpret_cast<f16x8*>(&tmp[8]);
    }
  }
  __syncthreads();
  for (int step = 0; step < 16; ++step) {
    f16x8 bf[8];
    loadBfrag(wes + (size_t)step * 16384, bf, wn, fr, fg);
    f16x8 af[2];
    #pragma unroll
    for (int mf = 0; mf < 2; ++mf)
      af[mf] = *reinterpret_cast<const f16x8*>(&As[(wm + mf * 16 + fr) * 520 + step * 32 + fg * 8]);
    #pragma unroll
    for (int nf = 0; nf < 8; ++nf)
      #pragma unroll
      for (int mf = 0; mf < 2; ++mf)
        acc[mf][nf] = __builtin_amdgcn_mfma_f32_16x16x32_f16(af[mf], bf[nf], acc[mf][nf], 0, 0, 0);
  }
  __syncthreads();
  // epilogue 1: hn -> As (f16 bounce, stride 520)
  #pragma unroll
  for (int nf = 0; nf < 8; ++nf) {
    int c = wn + nf * 16 + fr;
    float b_ = be[c];
    #pragma unroll
    for (int mf = 0; mf < 2; ++mf)
      #pragma unroll
      for (int i = 0; i < 4; ++i) {
        int rl = wm + mf * 16 + fg * 4 + i;
        As[rl * 520 + c] = (f16)fmaxf(acc[mf][nf][i] + b_, 0.f);
      }
  }
  __syncthreads();
  // epilogue 2: per-column segmented run-accumulate over sorted batch ids
  {
    const int c = tid;
    float s = 0.f;
    int pb = bat[0];
    #pragma unroll 1
    for (int r = 0; r < 64; ++r) {
      if (n0 + r >= NN) break;
      int b = bat[r];
      if (b != pb) {
        atomicAdd(&pooled[(size_t)pb * 512 + c], s);
        s = 0.f; pb = b;
      }
      s += (float)As[r * 520 + c];
    }
    atomicAdd(&pooled[(size_t)pb * 512 + c], s);
  }
}

// ---------------- ffn1: double-buffered B ----------------
__global__ __launch_bounds__(512, 1)
void ffn1(const f16* __restrict__ ph, const f16* __restrict__ wf,
          const float* __restrict__ b1, f16* __restrict__ t1) {
  __shared__ f16 As[64 * 520];
  __shared__ f16 Bs[2][512 * 40];
  const int tid = threadIdx.x, lane = tid & 63, wid = tid >> 6;
  const int fr = lane & 15, fg = lane >> 4;
  const int wm = (wid >> 2) * 32, wn = (wid & 3) * 128;
  const int n0 = blockIdx.x * 64;
  { int r = tid >> 3, hs = (tid & 7) * 64;
    #pragma unroll
    for (int j = 0; j < 8; ++j)
      *reinterpret_cast<f16x8*>(&As[r * 520 + hs + j * 8]) =
          *reinterpret_cast<const f16x8*>(&ph[(size_t)(n0 + r) * 512 + hs + j * 8]); }
  stageB512(wf, Bs[0], tid);
  __syncthreads();
  f32x4 acc[2][8] = {};
  for (int step = 0; step < 16; ++step) {
    const int cur = step & 1;
    f16x8 pf[4];
    if (step < 15) {
      const f16* wsrc = wf + (size_t)(step + 1) * 16384;
      #pragma unroll
      for (int j = 0; j < 4; ++j)
        pf[j] = *reinterpret_cast<const f16x8*>(&wsrc[(size_t)(tid * 4 + j) * 8]);
    }
    mstep8<520>(As, Bs[cur], acc, wm, wn, fr, fg, step * 32);
    if (step < 15) {
      #pragma unroll
      for (int j = 0; j < 4; ++j) {
        int u = tid * 4 + j;
        *reinterpret_cast<f16x8*>(&Bs[cur ^ 1][(u >> 2) * 40 + (u & 3) * 8]) = pf[j];
      }
    }
    __syncthreads();
  }
  f16* q16 = As;
  #pragma unroll
  for (int nf = 0; nf < 8; ++nf) {
    int c = wn + nf * 16 + fr;
    float b_ = b1[c];
    #pragma unroll
    for (int mf = 0; mf < 2; ++mf)
      #pragma unroll
      for (int i = 0; i < 4; ++i) {
        int r = wm + mf * 16 + fg * 4 + i;
        q16[r * 512 + c] = (f16)fmaxf(acc[mf][nf][i] + b_, 0.f);
      }
  }
  __syncthreads();
  #pragma unroll
  for (int j = 0; j < 8; ++j)
    *reinterpret_cast<f16x8*>(&t1[(size_t)n0 * 512 + tid * 64 + j * 8]) =
        *reinterpret_cast<const f16x8*>(&q16[tid * 64 + j * 8]);
}

__global__ void cast_ph(const float* __restrict__ pooled, f16* __restrict__ ph) {
  int id = blockIdx.x * 256 + threadIdx.x;
  if (id >= NB * 64) return;
  int k = id * 8;
  f16 v[8];
  #pragma unroll
  for (int i = 0; i < 8; ++i) v[i] = (f16)pooled[k + i];
  *reinterpret_cast<f16x8*>(&ph[k]) = *reinterpret_cast<f16x8*>(&v[0]);
}

__global__ void final_out(const f16* __restrict__ t, const float* __restrict__ W2,
                          const float* __restrict__ b2, float* __restrict__ out) {
  int id = blockIdx.x * 256 + threadIdx.x;
  if (id >= NB * 64) return;
  int b = id >> 6, lane = id & 63;
  f16x8 v = *reinterpret_cast<const f16x8*>(&t[(size_t)b * HD + lane * 8]);
  float s = 0.f;
  #pragma unroll
  for (int i = 0; i < 8; ++i) s += (float)v[i] * W2[lane * 8 + i];
  #pragma unroll
  for (int o = 32; o > 0; o >>= 1) s += __shfl_down(s, o);
  if (lane == 0) out[b] = s + b2[0];
}

extern "C" void kernel_launch(void* const* d_in, const int* in_sizes, int n_in,
                              void* d_out, int out_size, void* d_ws, size_t ws_size,
                              hipStream_t stream) {
  const float* x      = (const float*)d_in[0];
  const float* ea     = (const float*)d_in[1];
  const int*   ei     = (const int*)d_in[2];
  const int*   batch  = (const int*)d_in[3];
  const float* W_init = (const float*)d_in[4];
  const float* b_init = (const float*)d_in[5];
  const float* W_conv = (const float*)d_in[6];
  const float* b_conv = (const float*)d_in[7];
  const float* W_e2n  = (const float*)d_in[8];
  const float* b_e2n  = (const float*)d_in[9];
  const float* W_ffn1 = (const float*)d_in[10];
  const float* b_ffn1 = (const float*)d_in[11];
  const float* W_ffn2 = (const float*)d_in[12];
  const float* b_ffn2 = (const float*)d_in[13];
  const int* row = ei;
  const int* col = ei + NE;
  float* out = (float*)d_out;

  if (ws_size < WS_NEEDED) {
    diag<<<(out_size + 255) / 256, 256, 0, stream>>>(out, out_size, (float)(ws_size >> 20));
    return;
  }

  char* ws = (char*)d_ws;
  char*  h8   = ws + O_H8;
  float* sce  = (float*)(ws + O_SCE);
  char*  msgq = ws + O_SHR;
  float* scm  = (float*)(ws + O_SHR + 40960000UL);
  char*  nb8  = ws + O_SHR;
  float* scn  = (float*)(ws + O_SHR + 51200000UL);
  f16*   wt   = (f16*)(ws + O_WT);
  int*   off  = (int*)(ws + O_OFF);
  int*   eid  = (int*)(ws + O_EID);
  float* pooled = (float*)(ws + V_POOL);
  f16*   ph   = (f16*)(ws + V_PH);
  f16*   t1   = (f16*)(ws + V_T1);
  int*   cnt  = (int*)(ws + V_CNT);
  int*   fill = (int*)(ws + V_FILL);
  int*   bsum = (int*)(ws + V_BSUM);

  f16* wi  = wt;
  f16* wc  = wi + 160 * 512;
  f16* wex = wc + 5 * 512 * 512;
  f16* wes = wex + 160 * 512;
  f16* wf1 = wes + 512 * 512;

  transcast<<<(512 * 160 + 255) / 256, 256, 0, stream>>>(W_init, wi, 147, 160);
  for (int l = 0; l < 5; ++l)
    transcast<<<(512 * 512 + 255) / 256, 256, 0, stream>>>(
        W_conv + (size_t)l * 262144, wc + (size_t)l * 262144, 512, 512);
  transcast<<<(512 * 160 + 255) / 256, 256, 0, stream>>>(W_e2n, wex, 133, 160);
  transcast<<<(512 * 512 + 255) / 256, 256, 0, stream>>>(W_e2n + 133 * 512, wes, 512, 512);
  transcast<<<(512 * 512 + 255) / 256, 256, 0, stream>>>(W_ffn1, wf1, 512, 512);

  zero16<<<(25000 + 255) / 256, 256, 0, stream>>>((ulong2*)cnt, 25000);
  countK<<<(NE + 255) / 256, 256, 0, stream>>>(col, cnt);
  scanA<<<98, 1024, 0, stream>>>(cnt, fill, bsum);
  scanB<<<1, 64, 0, stream>>>(bsum, 98);
  scanC<<<98, 1024, 0, stream>>>(cnt, fill, bsum, off);
  scatterK<<<(NE + 255) / 256, 256, 0, stream>>>(col, fill, eid);

  convup<0><<<2500, 512, 0, stream>>>(x, ea, row, wi, b_init, nullptr,
                                      h8, sce, nullptr, nullptr, 0);
  convup<0><<<2500, 512, 0, stream>>>(x, ea, row, wi, b_init, nullptr,
                                      h8, sce, nullptr, nullptr, 256);
  for (int l = 0; l < 5; ++l) {
    zk<<<5000, 256, 0, stream>>>(h8, sce, wc + (size_t)l * 262144);
    msgk<0><<<25000, 256, 0, stream>>>(h8, sce, off, eid, msgq, scm);
    convup<1><<<2500, 512, 0, stream>>>(x, ea, row, wi, b_init, b_conv + l * 512,
                                        h8, sce, msgq, scm, 0);
    msgk<256><<<25000, 256, 0, stream>>>(h8, sce, off, eid, msgq, scm);
    convup<1><<<2500, 512, 0, stream>>>(x, ea, row, wi, b_init, b_conv + l * 512,
                                        h8, sce, msgq, scm, 256);
  }
  tker<<<25000, 256, 0, stream>>>(h8, sce, off, eid, nb8, scn);
  zero16<<<(524288 + 255) / 256, 256, 0, stream>>>((ulong2*)pooled, 524288);
  e2n<<<1563, 512, 0, stream>>>(x, nb8, scn, wex, wes, b_e2n, batch, pooled);
  cast_ph<<<(NB * 64 + 255) / 256, 256, 0, stream>>>(pooled, ph);
  ffn1<<<64, 512, 0, stream>>>(ph, wf1, b_ffn1, t1);
  final_out<<<(NB * 64 + 255) / 256, 256, 0, stream>>>(t1, W_ffn2, b_ffn2, out);
}

// Round 20
// 2431.532 us; speedup vs baseline: 1.0762x; 1.0762x over previous
//
#include <hip/hip_runtime.h>

typedef _Float16 f16;
typedef _Float16 f16x2 __attribute__((ext_vector_type(2)));
typedef _Float16 f16x4 __attribute__((ext_vector_type(4)));
typedef _Float16 f16x8 __attribute__((ext_vector_type(8)));
typedef float f32x4 __attribute__((ext_vector_type(4)));

#define NN 100000
#define NE 160000
#define NB 4096
#define HD 512

// ---- workspace layout (WS_NEEDED = 146,477,712 B < 160 MiB) ----
#define O_H8    0UL
#define O_SCE   81920000UL
#define O_SHR   87040000UL
#define O_WT    141440000UL
#define O_OFF   145437696UL
#define O_EID   145837712UL
#define WS_NEEDED 146477712UL
#define V_POOL  0UL
#define V_PH    8388608UL
#define V_T1    12582912UL
#define V_CNT   16777216UL
#define V_FILL  17177232UL
#define V_BSUM  17577248UL

__global__ void zero16(ulong2* __restrict__ p, long n) {
  long i = (long)blockIdx.x * 256 + threadIdx.x;
  if (i < n) p[i] = ulong2{0UL, 0UL};
}
__global__ void diag(float* __restrict__ out, int n, float v) {
  int i = blockIdx.x * 256 + threadIdx.x;
  if (i < n) out[i] = v;
}

__global__ void transcast(const float* __restrict__ src, f16* __restrict__ dst,
                          int Kreal, int Kpad) {
  int id = blockIdx.x * 256 + threadIdx.x;
  if (id >= 512 * Kpad) return;
  int n = id / Kpad, k = id % Kpad;
  dst[((k >> 5) * 512 + n) * 32 + (k & 31)] =
      (k < Kreal) ? (f16)src[(size_t)k * 512 + n] : (f16)0.f;
}

// ---------------- CSR by col ----------------
__global__ void countK(const int* __restrict__ col, int* __restrict__ cnt) {
  int e = blockIdx.x * 256 + threadIdx.x;
  if (e < NE) atomicAdd(&cnt[col[e]], 1);
}
__global__ __launch_bounds__(1024) void scanA(const int* __restrict__ cnt,
                                              int* __restrict__ incl, int* __restrict__ bsum) {
  __shared__ int s[1024];
  int i = blockIdx.x * 1024 + threadIdx.x;
  s[threadIdx.x] = (i < NN) ? cnt[i] : 0;
  __syncthreads();
  for (int d = 1; d < 1024; d <<= 1) {
    int t = (threadIdx.x >= d) ? s[threadIdx.x - d] : 0;
    __syncthreads();
    s[threadIdx.x] += t;
    __syncthreads();
  }
  if (i < NN) incl[i] = s[threadIdx.x];
  if (threadIdx.x == 1023) bsum[blockIdx.x] = s[1023];
}
__global__ void scanB(int* bsum, int nb) {
  if (threadIdx.x == 0 && blockIdx.x == 0) {
    int run = 0;
    for (int i = 0; i < nb; ++i) { int t = bsum[i]; bsum[i] = run; run += t; }
  }
}
__global__ __launch_bounds__(1024) void scanC(const int* __restrict__ cnt,
                                              int* __restrict__ incl_fill,
                                              const int* __restrict__ bsum,
                                              int* __restrict__ off) {
  int i = blockIdx.x * 1024 + threadIdx.x;
  if (i >= NN) return;
  int g = incl_fill[i] + bsum[blockIdx.x];
  off[i + 1] = g;
  incl_fill[i] = g - cnt[i];
  if (i == 0) off[0] = 0;
}
__global__ void scatterK(const int* __restrict__ col, int* __restrict__ fill,
                         int* __restrict__ eid) {
  int e = blockIdx.x * 256 + threadIdx.x;
  if (e >= NE) return;
  int p = atomicAdd(&fill[col[e]], 1);
  eid[p] = e;
}

// ---------------- msgk<C0>: leave-one-out message; single CSR walk with
// register cache for the first 8 edges (avg degree 1.6 -> ~all nodes).
template<int C0>
__global__ __launch_bounds__(256, 4)
void msgk(const char* __restrict__ z8, const float* __restrict__ sce,
          const int* __restrict__ off, const int* __restrict__ eid,
          char* __restrict__ msgq, float* __restrict__ scm) {
  int tid = threadIdx.x, wid = tid >> 6, lane = tid & 63;
  int n = blockIdx.x * 4 + wid;
  int s0 = off[n], s1 = off[n + 1];
  int cnt = s1 - s0;
  int g = lane >> 4;
  float a[4] = {0.f, 0.f, 0.f, 0.f};
  int ec[8]; unsigned uc[8]; float scc[8];
  #pragma unroll
  for (int i = 0; i < 8; ++i) {
    if (i < cnt) {
      int e = eid[s0 + i];
      ec[i] = e;
      scc[i] = sce[e * 8 + (C0 >> 6) + g];
      uc[i] = *reinterpret_cast<const unsigned*>(z8 + (size_t)e * 512 + C0 + lane * 4);
      #pragma unroll
      for (int b = 0; b < 4; ++b)
        a[b] += (float)(char)((uc[i] >> (8 * b)) & 0xff) * scc[i];
    }
  }
  for (int p = s0 + 8; p < s1; ++p) {
    int e = eid[p];
    float sc = sce[e * 8 + (C0 >> 6) + g];
    unsigned u = *reinterpret_cast<const unsigned*>(z8 + (size_t)e * 512 + C0 + lane * 4);
    #pragma unroll
    for (int b = 0; b < 4; ++b)
      a[b] += (float)(char)((u >> (8 * b)) & 0xff) * sc;
  }
  #pragma unroll
  for (int i = 0; i < 8; ++i) {
    if (i < cnt) {
      int f = ec[i] ^ 1;
      float mv[4]; float m = 0.f;
      #pragma unroll
      for (int b = 0; b < 4; ++b) {
        mv[b] = a[b] - (float)(char)((uc[i] >> (8 * b)) & 0xff) * scc[i];
        m = fmaxf(m, fabsf(mv[b]));
      }
      #pragma unroll
      for (int d = 1; d < 16; d <<= 1) m = fmaxf(m, __shfl_xor(m, d));
      float s2 = (m > 0.f) ? m / 127.f : 1.f;
      if ((lane & 15) == 0) scm[f * 4 + g] = s2;
      unsigned q = 0;
      #pragma unroll
      for (int b = 0; b < 4; ++b) {
        int qi = __float2int_rn(mv[b] / s2);
        qi = min(127, max(-127, qi));
        q |= ((unsigned)(unsigned char)(char)qi) << (8 * b);
      }
      *reinterpret_cast<unsigned*>(msgq + (size_t)f * 256 + lane * 4) = q;
    }
  }
  for (int p = s0 + 8; p < s1; ++p) {
    int e = eid[p];
    int f = e ^ 1;
    float sc = sce[e * 8 + (C0 >> 6) + g];
    unsigned u = *reinterpret_cast<const unsigned*>(z8 + (size_t)e * 512 + C0 + lane * 4);
    float mv[4]; float m = 0.f;
    #pragma unroll
    for (int b = 0; b < 4; ++b) {
      mv[b] = a[b] - (float)(char)((u >> (8 * b)) & 0xff) * sc;
      m = fmaxf(m, fabsf(mv[b]));
    }
    #pragma unroll
    for (int d = 1; d < 16; d <<= 1) m = fmaxf(m, __shfl_xor(m, d));
    float s2 = (m > 0.f) ? m / 127.f : 1.f;
    if ((lane & 15) == 0) scm[f * 4 + g] = s2;
    unsigned q = 0;
    #pragma unroll
    for (int b = 0; b < 4; ++b) {
      int qi = __float2int_rn(mv[b] / s2);
      qi = min(127, max(-127, qi));
      q |= ((unsigned)(unsigned char)(char)qi) << (8 * b);
    }
    *reinterpret_cast<unsigned*>(msgq + (size_t)f * 256 + lane * 4) = q;
  }
}

// ---------------- tker: s_node = segsum(h,col) ----------------
__global__ __launch_bounds__(256, 4)
void tker(const char* __restrict__ h8, const float* __restrict__ sce,
          const int* __restrict__ off, const int* __restrict__ eid,
          char* __restrict__ nb8, float* __restrict__ scn) {
  int tid = threadIdx.x, wid = tid >> 6, lane = tid & 63;
  int n = blockIdx.x * 4 + wid;
  int s0 = off[n], s1 = off[n + 1];
  int g = lane >> 3;
  float a[8] = {0.f,0.f,0.f,0.f,0.f,0.f,0.f,0.f};
  for (int p = s0; p < s1; ++p) {
    int e = eid[p];
    float sc = sce[e * 8 + g];
    uint2 u = *reinterpret_cast<const uint2*>(h8 + (size_t)e * 512 + lane * 8);
    #pragma unroll
    for (int b = 0; b < 4; ++b) {
      a[b]     += (float)((u.x >> (8 * b)) & 0xff) * sc;
      a[4 + b] += (float)((u.y >> (8 * b)) & 0xff) * sc;
    }
  }
  float m = 0.f;
  #pragma unroll
  for (int j = 0; j < 8; ++j) m = fmaxf(m, a[j]);
  #pragma unroll
  for (int d = 1; d < 8; d <<= 1) m = fmaxf(m, __shfl_xor(m, d));
  float s2 = (m > 0.f) ? m / 255.f : 1.f;
  if ((lane & 7) == 0) scn[n * 8 + g] = s2;
  unsigned lo = 0, hi = 0;
  #pragma unroll
  for (int b = 0; b < 4; ++b) {
    int q0 = __float2int_rn(a[b] / s2);     q0 = min(255, max(0, q0));
    int q1 = __float2int_rn(a[4 + b] / s2); q1 = min(255, max(0, q1));
    lo |= ((unsigned)q0) << (8 * b);
    hi |= ((unsigned)q1) << (8 * b);
  }
  *reinterpret_cast<uint2*>(nb8 + (size_t)n * 512 + lane * 8) = uint2{lo, hi};
}

// ---------------- shared GEMM helpers ----------------
static __device__ __forceinline__ void stageB512(const f16* __restrict__ wsrc,
                                                 f16* __restrict__ Bs, int tid) {
  #pragma unroll
  for (int j = 0; j < 4; ++j) {
    int u = tid * 4 + j;
    *reinterpret_cast<f16x8*>(&Bs[(u >> 2) * 40 + (u & 3) * 8]) =
        *reinterpret_cast<const f16x8*>(&wsrc[u * 8]);
  }
}
template<int AS>
static __device__ __forceinline__ void mstep8(const f16* __restrict__ As,
                                              const f16* __restrict__ Bs,
                                              f32x4 acc[2][8], int wm, int wn,
                                              int fr, int fg, int ko) {
  f16x8 af[2];
  #pragma unroll
  for (int mf = 0; mf < 2; ++mf)
    af[mf] = *reinterpret_cast<const f16x8*>(&As[(wm + mf * 16 + fr) * AS + ko + fg * 8]);
  #pragma unroll
  for (int nf = 0; nf < 8; ++nf) {
    f16x8 bf = *reinterpret_cast<const f16x8*>(&Bs[(wn + nf * 16 + fr) * 40 + fg * 8]);
    #pragma unroll
    for (int mf = 0; mf < 2; ++mf)
      acc[mf][nf] = __builtin_amdgcn_mfma_f32_16x16x32_f16(af[mf], bf, acc[mf][nf], 0, 0, 0);
  }
}

// B fragments straight from global (L2-hot weights) — used by e2n.
static __device__ __forceinline__ void loadBfrag(const f16* __restrict__ wp,
                                                 f16x8 bf[8], int wn, int fr, int fg) {
  #pragma unroll
  for (int nf = 0; nf < 8; ++nf)
    bf[nf] = *reinterpret_cast<const f16x8*>(&wp[(size_t)(wn + nf * 16 + fr) * 32 + fg * 8]);
}

static __device__ __forceinline__ f16x2 pkfma(f16x2 a, f16x2 b, f16x2 c) {
  f16x2 r;
  asm("v_pk_fma_f16 %0, %1, %2, %3" : "=v"(r) : "v"(a), "v"(b), "v"(c));
  return r;
}

// vectorized x-row stage: 4x dwordx4 + scalar tail, write f16x4 to LDS row
static __device__ __forceinline__ void stageXrow(const float* __restrict__ xr,
                                                 f16* __restrict__ dstRow, int s) {
  #pragma unroll
  for (int j = 0; j < 4; ++j) {
    float v[4];
    __builtin_memcpy(v, xr + 4 * s + 32 * j, 16);
    f16 t4[4];
    #pragma unroll
    for (int b = 0; b < 4; ++b) t4[b] = (f16)v[b];
    *reinterpret_cast<f16x4*>(&dstRow[4 * s + 32 * j]) = *reinterpret_cast<f16x4*>(t4);
  }
  if (s < 5) dstRow[128 + s] = (f16)xr[128 + s];
}

// ---------------- zk: z = h @ W. Dequant-at-stage in 2 K-phases (proven r18) ----------------
__global__ __launch_bounds__(512, 4)
void zk(char* __restrict__ h8, float* __restrict__ sce, const f16* __restrict__ wst) {
  __shared__ f16 Af[64 * 264];        // half-K (256) f16 A tile, row stride 264
  __shared__ f16 Bs[512 * 40];
  const int tid = threadIdx.x, lane = tid & 63, wid = tid >> 6;
  const int fr = lane & 15, fg = lane >> 4;
  const int wm = (wid >> 2) * 32, wn = (wid & 3) * 128;
  const int e0 = blockIdx.x * 64;
  const int sr = tid >> 3;
  const int sc8 = tid & 7;

  auto stageA = [&](int phase) {
    const int kb = phase * 256 + sc8 * 32;
    float sa = sce[(size_t)(e0 + sr) * 8 + (kb >> 6)];
    const f16 sh = (f16)sa;
    const f16 bh = (f16)(-1024.f * sa);
    f16x2 s2; s2[0] = sh; s2[1] = sh;
    f16x2 b2; b2[0] = bh; b2[1] = bh;
    const int4* src = reinterpret_cast<const int4*>(h8 + (size_t)(e0 + sr) * 512 + kb);
    f16* dst = &Af[sr * 264 + sc8 * 32];
    #pragma unroll
    for (int j = 0; j < 2; ++j) {
      int4 w = src[j];
      unsigned vv[4] = {(unsigned)w.x, (unsigned)w.y, (unsigned)w.z, (unsigned)w.w};
      #pragma unroll
      for (int q = 0; q < 2; ++q) {
        unsigned p0 = __builtin_amdgcn_perm(0x64646464u, vv[2*q],     0x05010400u);
        unsigned p1 = __builtin_amdgcn_perm(0x64646464u, vv[2*q],     0x05030402u);
        unsigned p2 = __builtin_amdgcn_perm(0x64646464u, vv[2*q + 1], 0x05010400u);
        unsigned p3 = __builtin_amdgcn_perm(0x64646464u, vv[2*q + 1], 0x05030402u);
        uint4 o;
        o.x = __builtin_bit_cast(unsigned, pkfma(__builtin_bit_cast(f16x2, p0), s2, b2));
        o.y = __builtin_bit_cast(unsigned, pkfma(__builtin_bit_cast(f16x2, p1), s2, b2));
        o.z = __builtin_bit_cast(unsigned, pkfma(__builtin_bit_cast(f16x2, p2), s2, b2));
        o.w = __builtin_bit_cast(unsigned, pkfma(__builtin_bit_cast(f16x2, p3), s2, b2));
        *reinterpret_cast<uint4*>(dst + j * 16 + q * 8) = o;
      }
    }
  };

  stageA(0);
  f32x4 acc[2][8] = {};
  for (int step = 0; step < 16; ++step) {
    if (step == 8) stageA(1);
    stageB512(wst + (size_t)step * 16384, Bs, tid);
    __syncthreads();
    const int ko = (step & 7) * 32;
    f16x8 af[2];
    #pragma unroll
    for (int mf = 0; mf < 2; ++mf)
      af[mf] = *reinterpret_cast<const f16x8*>(&Af[(wm + mf * 16 + fr) * 264 + ko + fg * 8]);
    #pragma unroll
    for (int nf = 0; nf < 8; ++nf) {
      f16x8 bf = *reinterpret_cast<const f16x8*>(&Bs[(wn + nf * 16 + fr) * 40 + fg * 8]);
      #pragma unroll
      for (int mf = 0; mf < 2; ++mf)
        acc[mf][nf] = __builtin_amdgcn_mfma_f32_16x16x32_f16(af[mf], bf, acc[mf][nf], 0, 0, 0);
    }
    __syncthreads();
  }
  float scA[2][4], scB[2][4];
  #pragma unroll
  for (int mf = 0; mf < 2; ++mf)
    #pragma unroll
    for (int i = 0; i < 4; ++i) {
      float mA = 0.f, mB = 0.f;
      #pragma unroll
      for (int nf = 0; nf < 4; ++nf) mA = fmaxf(mA, fabsf(acc[mf][nf][i]));
      #pragma unroll
      for (int nf = 4; nf < 8; ++nf) mB = fmaxf(mB, fabsf(acc[mf][nf][i]));
      #pragma unroll
      for (int d = 1; d < 16; d <<= 1) {
        mA = fmaxf(mA, __shfl_xor(mA, d));
        mB = fmaxf(mB, __shfl_xor(mB, d));
      }
      scA[mf][i] = (mA > 0.f) ? mA / 127.f : 1.f;
      scB[mf][i] = (mB > 0.f) ? mB / 127.f : 1.f;
      if (fr == 0) {
        int r = wm + mf * 16 + fg * 4 + i;
        sce[(size_t)(e0 + r) * 8 + (wn >> 6)]     = scA[mf][i];
        sce[(size_t)(e0 + r) * 8 + (wn >> 6) + 1] = scB[mf][i];
      }
    }
  char* q8 = (char*)&Bs[0];
  #pragma unroll
  for (int mf = 0; mf < 2; ++mf)
    #pragma unroll
    for (int nf = 0; nf < 8; ++nf) {
      int c = wn + nf * 16 + fr;
      #pragma unroll
      for (int i = 0; i < 4; ++i) {
        int r = wm + mf * 16 + fg * 4 + i;
        float s = (nf < 4) ? scA[mf][i] : scB[mf][i];
        int q = __float2int_rn(acc[mf][nf][i] / s);
        q8[r * 512 + c] = (char)min(127, max(-127, q));
      }
    }
  __syncthreads();
  { int4* dst = reinterpret_cast<int4*>(h8 + (size_t)e0 * 512);
    const int4* s4 = reinterpret_cast<const int4*>(q8);
    #pragma unroll
    for (int j = 0; j < 4; ++j) dst[tid * 4 + j] = s4[tid * 4 + j]; }
}

// ---------------- convup: half-width, double-buffered B; vectorized gather ----------------
template<int MODE>
__global__ __launch_bounds__(512, 2)
void convup(const float* __restrict__ x, const float* __restrict__ ea,
            const int* __restrict__ row, const f16* __restrict__ wi,
            const float* __restrict__ bi, const float* __restrict__ bc,
            char* __restrict__ h8, float* __restrict__ sce,
            const char* __restrict__ msgq, const float* __restrict__ scm,
            int c0) {
  __shared__ f16 As[64 * 168];
  __shared__ f16 Bs[2][256 * 40];
  __shared__ char m8s[64 * 256];
  __shared__ float scmL[64 * 4];
  const int tid = threadIdx.x, lane = tid & 63, wid = tid >> 6;
  const int fr = lane & 15, fg = lane >> 4;
  const int wm = (wid >> 2) * 32, wn = (wid & 3) * 64;
  const int e0 = blockIdx.x * 64;

  { // stage A1 = [x[row]|ea] pad->160 (vectorized); msg tile for MODE 1
    int r = tid >> 3, s = tid & 7;
    int rid = row[e0 + r];
    stageXrow(x + (size_t)rid * 133, &As[r * 168], s);
    if (s < 7) {
      float2 e2 = *reinterpret_cast<const float2*>(ea + (size_t)(e0 + r) * 14 + 2 * s);
      As[r * 168 + 133 + 2 * s]     = (f16)e2.x;
      As[r * 168 + 133 + 2 * s + 1] = (f16)e2.y;
    }
    for (int k = 147 + s; k < 160; k += 8) As[r * 168 + k] = (f16)0.f;
    if (MODE == 1) {
      const int4* ms = reinterpret_cast<const int4*>(msgq + (size_t)(e0 + r) * 256 + s * 32);
      int4* md = reinterpret_cast<int4*>(m8s + r * 256 + s * 32);
      md[0] = ms[0]; md[1] = ms[1];
      if (s < 4) scmL[r * 4 + s] = scm[(size_t)(e0 + r) * 4 + s];
    }
  }
  { // prologue: stage B step 0
    #pragma unroll
    for (int j = 0; j < 2; ++j) {
      int u = tid * 2 + j;
      *reinterpret_cast<f16x8*>(&Bs[0][(u >> 2) * 40 + (u & 3) * 8]) =
          *reinterpret_cast<const f16x8*>(&wi[(size_t)c0 * 32 + (size_t)u * 8]);
    }
  }
  __syncthreads();
  f32x4 acc[2][4] = {};
  for (int step = 0; step < 5; ++step) {
    const int cur = step & 1;
    f16x8 pf[2];
    if (step < 4) {
      const f16* wsrc = wi + (size_t)(step + 1) * 16384 + (size_t)c0 * 32;
      #pragma unroll
      for (int j = 0; j < 2; ++j)
        pf[j] = *reinterpret_cast<const f16x8*>(&wsrc[(size_t)(tid * 2 + j) * 8]);
    }
    f16x8 af[2];
    #pragma unroll
    for (int mf = 0; mf < 2; ++mf)
      af[mf] = *reinterpret_cast<const f16x8*>(&As[(wm + mf * 16 + fr) * 168 + step * 32 + fg * 8]);
    #pragma unroll
    for (int nf = 0; nf < 4; ++nf) {
      f16x8 bf = *reinterpret_cast<const f16x8*>(&Bs[cur][(wn + nf * 16 + fr) * 40 + fg * 8]);
      #pragma unroll
      for (int mf = 0; mf < 2; ++mf)
        acc[mf][nf] = __builtin_amdgcn_mfma_f32_16x16x32_f16(af[mf], bf, acc[mf][nf], 0, 0, 0);
    }
    if (step < 4) {
      #pragma unroll
      for (int j = 0; j < 2; ++j) {
        int u = tid * 2 + j;
        *reinterpret_cast<f16x8*>(&Bs[cur ^ 1][(u >> 2) * 40 + (u & 3) * 8]) = pf[j];
      }
    }
    __syncthreads();
  }
  // epilogue: h0 = relu(gemm+bi); MODE1: h' = relu(h0 + bc + msg)
  #pragma unroll
  for (int nf = 0; nf < 4; ++nf) {
    int cl = wn + nf * 16 + fr;
    int cg = c0 + cl;
    float bi_ = bi[cg];
    float bc_ = (MODE == 1) ? bc[cg] : 0.f;
    #pragma unroll
    for (int mf = 0; mf < 2; ++mf)
      #pragma unroll
      for (int i = 0; i < 4; ++i) {
        int r = wm + mf * 16 + fg * 4 + i;
        float v = fmaxf(acc[mf][nf][i] + bi_, 0.f);
        if (MODE == 1) {
          float mv = (float)(char)m8s[r * 256 + cl] * scmL[r * 4 + (cl >> 6)];
          v = fmaxf(v + bc_ + mv, 0.f);
        }
        acc[mf][nf][i] = v;
      }
  }
  float sc_[2][4];
  #pragma unroll
  for (int mf = 0; mf < 2; ++mf)
    #pragma unroll
    for (int i = 0; i < 4; ++i) {
      float m = 0.f;
      #pragma unroll
      for (int nf = 0; nf < 4; ++nf) m = fmaxf(m, acc[mf][nf][i]);
      #pragma unroll
      for (int d = 1; d < 16; d <<= 1) m = fmaxf(m, __shfl_xor(m, d));
      sc_[mf][i] = (m > 0.f) ? m / 255.f : 1.f;
      if (fr == 0)
        sce[(size_t)(e0 + wm + mf * 16 + fg * 4 + i) * 8 + (c0 >> 6) + (wn >> 6)] = sc_[mf][i];
    }
  __syncthreads();
  #pragma unroll
  for (int mf = 0; mf < 2; ++mf)
    #pragma unroll
    for (int nf = 0; nf < 4; ++nf) {
      int cl = wn + nf * 16 + fr;
      #pragma unroll
      for (int i = 0; i < 4; ++i) {
        int r = wm + mf * 16 + fg * 4 + i;
        int q = __float2int_rn(acc[mf][nf][i] / sc_[mf][i]);
        m8s[r * 256 + cl] = (char)(unsigned char)min(255, max(0, q));
      }
    }
  __syncthreads();
  { int r = tid >> 3, s = tid & 7;
    int4* dst = reinterpret_cast<int4*>(h8 + (size_t)(e0 + r) * 512 + c0 + s * 32);
    const int4* sp = reinterpret_cast<const int4*>(m8s + r * 256 + s * 32);
    dst[0] = sp[0]; dst[1] = sp[1]; }
}

// ---------------- e2n: B direct from L2, barrier-free GEMMs; vectorized gather ----------------
__global__ __launch_bounds__(512, 4)
void e2n(const float* __restrict__ x, const char* __restrict__ nb8,
         const float* __restrict__ scn, const f16* __restrict__ wex,
         const f16* __restrict__ wes, const float* __restrict__ be,
         const int* __restrict__ batch, float* __restrict__ pooled) {
  __shared__ f16 As[64 * 520];
  __shared__ int bat[64];
  const int tid = threadIdx.x, lane = tid & 63, wid = tid >> 6;
  const int fr = lane & 15, fg = lane >> 4;
  const int wm = (wid >> 2) * 32, wn = (wid & 3) * 128;
  const int n0 = blockIdx.x * 64;
  if (tid < 64) { int nn = n0 + tid; bat[tid] = (nn < NN) ? batch[nn] : 0; }
  { // x part, stride 168 (vectorized)
    int r = tid >> 3, s = tid & 7;
    int nid = min(n0 + r, NN - 1);
    stageXrow(x + (size_t)nid * 133, &As[r * 168], s);
    for (int k = 133 + s; k < 160; k += 8) As[r * 168 + k] = (f16)0.f;
  }
  __syncthreads();
  f32x4 acc[2][8] = {};
  for (int step = 0; step < 5; ++step) {
    f16x8 bf[8];
    loadBfrag(wex + (size_t)step * 16384, bf, wn, fr, fg);
    f16x8 af[2];
    #pragma unroll
    for (int mf = 0; mf < 2; ++mf)
      af[mf] = *reinterpret_cast<const f16x8*>(&As[(wm + mf * 16 + fr) * 168 + step * 32 + fg * 8]);
    #pragma unroll
    for (int nf = 0; nf < 8; ++nf)
      #pragma unroll
      for (int mf = 0; mf < 2; ++mf)
        acc[mf][nf] = __builtin_amdgcn_mfma_f32_16x16x32_f16(af[mf], bf[nf], acc[mf][nf], 0, 0, 0);
  }
  __syncthreads();
  { // re-stage As with dequantized s_node (u8 groupwise), stride 520
    int r = tid >> 3, s = tid & 7, kb = s * 64;
    int nid = min(n0 + r, NN - 1);
    float sc = scn[(size_t)nid * 8 + s];
    const int4* src = reinterpret_cast<const int4*>(nb8 + (size_t)nid * 512 + kb);
    #pragma unroll
    for (int j = 0; j < 4; ++j) {
      int4 w = src[j];
      unsigned vv[4] = {(unsigned)w.x, (unsigned)w.y, (unsigned)w.z, (unsigned)w.w};
      f16 tmp[16];
      #pragma unroll
      for (int q = 0; q < 4; ++q)
        #pragma unroll
        for (int b = 0; b < 4; ++b)
          tmp[q * 4 + b] = (f16)((float)((vv[q] >> (8 * b)) & 0xff) * sc);
      *reinterpret_cast<f16x8*>(&As[r * 520 + kb + j * 16])     = *reinterpret_cast<f16x8*>(&tmp[0]);
      *reinterpret_cast<f16x8*>(&As[r * 520 + kb + j * 16 + 8]) = *reinterpret_cast<f16x8*>(&tmp[8]);
    }
  }
  __syncthreads();
  for (int step = 0; step < 16; ++step) {
    f16x8 bf[8];
    loadBfrag(wes + (size_t)step * 16384, bf, wn, fr, fg);
    f16x8 af[2];
    #pragma unroll
    for (int mf = 0; mf < 2; ++mf)
      af[mf] = *reinterpret_cast<const f16x8*>(&As[(wm + mf * 16 + fr) * 520 + step * 32 + fg * 8]);
    #pragma unroll
    for (int nf = 0; nf < 8; ++nf)
      #pragma unroll
      for (int mf = 0; mf < 2; ++mf)
        acc[mf][nf] = __builtin_amdgcn_mfma_f32_16x16x32_f16(af[mf], bf[nf], acc[mf][nf], 0, 0, 0);
  }
  __syncthreads();
  // epilogue 1: hn -> As (f16 bounce, stride 520)
  #pragma unroll
  for (int nf = 0; nf < 8; ++nf) {
    int c = wn + nf * 16 + fr;
    float b_ = be[c];
    #pragma unroll
    for (int mf = 0; mf < 2; ++mf)
      #pragma unroll
      for (int i = 0; i < 4; ++i) {
        int rl = wm + mf * 16 + fg * 4 + i;
        As[rl * 520 + c] = (f16)fmaxf(acc[mf][nf][i] + b_, 0.f);
      }
  }
  __syncthreads();
  // epilogue 2: per-column segmented run-accumulate over sorted batch ids
  {
    const int c = tid;
    float s = 0.f;
    int pb = bat[0];
    #pragma unroll 1
    for (int r = 0; r < 64; ++r) {
      if (n0 + r >= NN) break;
      int b = bat[r];
      if (b != pb) {
        atomicAdd(&pooled[(size_t)pb * 512 + c], s);
        s = 0.f; pb = b;
      }
      s += (float)As[r * 520 + c];
    }
    atomicAdd(&pooled[(size_t)pb * 512 + c], s);
  }
}

// ---------------- ffn1: double-buffered B ----------------
__global__ __launch_bounds__(512, 1)
void ffn1(const f16* __restrict__ ph, const f16* __restrict__ wf,
          const float* __restrict__ b1, f16* __restrict__ t1) {
  __shared__ f16 As[64 * 520];
  __shared__ f16 Bs[2][512 * 40];
  const int tid = threadIdx.x, lane = tid & 63, wid = tid >> 6;
  const int fr = lane & 15, fg = lane >> 4;
  const int wm = (wid >> 2) * 32, wn = (wid & 3) * 128;
  const int n0 = blockIdx.x * 64;
  { int r = tid >> 3, hs = (tid & 7) * 64;
    #pragma unroll
    for (int j = 0; j < 8; ++j)
      *reinterpret_cast<f16x8*>(&As[r * 520 + hs + j * 8]) =
          *reinterpret_cast<const f16x8*>(&ph[(size_t)(n0 + r) * 512 + hs + j * 8]); }
  stageB512(wf, Bs[0], tid);
  __syncthreads();
  f32x4 acc[2][8] = {};
  for (int step = 0; step < 16; ++step) {
    const int cur = step & 1;
    f16x8 pf[4];
    if (step < 15) {
      const f16* wsrc = wf + (size_t)(step + 1) * 16384;
      #pragma unroll
      for (int j = 0; j < 4; ++j)
        pf[j] = *reinterpret_cast<const f16x8*>(&wsrc[(size_t)(tid * 4 + j) * 8]);
    }
    mstep8<520>(As, Bs[cur], acc, wm, wn, fr, fg, step * 32);
    if (step < 15) {
      #pragma unroll
      for (int j = 0; j < 4; ++j) {
        int u = tid * 4 + j;
        *reinterpret_cast<f16x8*>(&Bs[cur ^ 1][(u >> 2) * 40 + (u & 3) * 8]) = pf[j];
      }
    }
    __syncthreads();
  }
  f16* q16 = As;
  #pragma unroll
  for (int nf = 0; nf < 8; ++nf) {
    int c = wn + nf * 16 + fr;
    float b_ = b1[c];
    #pragma unroll
    for (int mf = 0; mf < 2; ++mf)
      #pragma unroll
      for (int i = 0; i < 4; ++i) {
        int r = wm + mf * 16 + fg * 4 + i;
        q16[r * 512 + c] = (f16)fmaxf(acc[mf][nf][i] + b_, 0.f);
      }
  }
  __syncthreads();
  #pragma unroll
  for (int j = 0; j < 8; ++j)
    *reinterpret_cast<f16x8*>(&t1[(size_t)n0 * 512 + tid * 64 + j * 8]) =
        *reinterpret_cast<const f16x8*>(&q16[tid * 64 + j * 8]);
}

__global__ void cast_ph(const float* __restrict__ pooled, f16* __restrict__ ph) {
  int id = blockIdx.x * 256 + threadIdx.x;
  if (id >= NB * 64) return;
  int k = id * 8;
  f16 v[8];
  #pragma unroll
  for (int i = 0; i < 8; ++i) v[i] = (f16)pooled[k + i];
  *reinterpret_cast<f16x8*>(&ph[k]) = *reinterpret_cast<f16x8*>(&v[0]);
}

__global__ void final_out(const f16* __restrict__ t, const float* __restrict__ W2,
                          const float* __restrict__ b2, float* __restrict__ out) {
  int id = blockIdx.x * 256 + threadIdx.x;
  if (id >= NB * 64) return;
  int b = id >> 6, lane = id & 63;
  f16x8 v = *reinterpret_cast<const f16x8*>(&t[(size_t)b * HD + lane * 8]);
  float s = 0.f;
  #pragma unroll
  for (int i = 0; i < 8; ++i) s += (float)v[i] * W2[lane * 8 + i];
  #pragma unroll
  for (int o = 32; o > 0; o >>= 1) s += __shfl_down(s, o);
  if (lane == 0) out[b] = s + b2[0];
}

extern "C" void kernel_launch(void* const* d_in, const int* in_sizes, int n_in,
                              void* d_out, int out_size, void* d_ws, size_t ws_size,
                              hipStream_t stream) {
  const float* x      = (const float*)d_in[0];
  const float* ea     = (const float*)d_in[1];
  const int*   ei     = (const int*)d_in[2];
  const int*   batch  = (const int*)d_in[3];
  const float* W_init = (const float*)d_in[4];
  const float* b_init = (const float*)d_in[5];
  const float* W_conv = (const float*)d_in[6];
  const float* b_conv = (const float*)d_in[7];
  const float* W_e2n  = (const float*)d_in[8];
  const float* b_e2n  = (const float*)d_in[9];
  const float* W_ffn1 = (const float*)d_in[10];
  const float* b_ffn1 = (const float*)d_in[11];
  const float* W_ffn2 = (const float*)d_in[12];
  const float* b_ffn2 = (const float*)d_in[13];
  const int* row = ei;
  const int* col = ei + NE;
  float* out = (float*)d_out;

  if (ws_size < WS_NEEDED) {
    diag<<<(out_size + 255) / 256, 256, 0, stream>>>(out, out_size, (float)(ws_size >> 20));
    return;
  }

  char* ws = (char*)d_ws;
  char*  h8   = ws + O_H8;
  float* sce  = (float*)(ws + O_SCE);
  char*  msgq = ws + O_SHR;
  float* scm  = (float*)(ws + O_SHR + 40960000UL);
  char*  nb8  = ws + O_SHR;
  float* scn  = (float*)(ws + O_SHR + 51200000UL);
  f16*   wt   = (f16*)(ws + O_WT);
  int*   off  = (int*)(ws + O_OFF);
  int*   eid  = (int*)(ws + O_EID);
  float* pooled = (float*)(ws + V_POOL);
  f16*   ph   = (f16*)(ws + V_PH);
  f16*   t1   = (f16*)(ws + V_T1);
  int*   cnt  = (int*)(ws + V_CNT);
  int*   fill = (int*)(ws + V_FILL);
  int*   bsum = (int*)(ws + V_BSUM);

  f16* wi  = wt;
  f16* wc  = wi + 160 * 512;
  f16* wex = wc + 5 * 512 * 512;
  f16* wes = wex + 160 * 512;
  f16* wf1 = wes + 512 * 512;

  transcast<<<(512 * 160 + 255) / 256, 256, 0, stream>>>(W_init, wi, 147, 160);
  for (int l = 0; l < 5; ++l)
    transcast<<<(512 * 512 + 255) / 256, 256, 0, stream>>>(
        W_conv + (size_t)l * 262144, wc + (size_t)l * 262144, 512, 512);
  transcast<<<(512 * 160 + 255) / 256, 256, 0, stream>>>(W_e2n, wex, 133, 160);
  transcast<<<(512 * 512 + 255) / 256, 256, 0, stream>>>(W_e2n + 133 * 512, wes, 512, 512);
  transcast<<<(512 * 512 + 255) / 256, 256, 0, stream>>>(W_ffn1, wf1, 512, 512);

  zero16<<<(25000 + 255) / 256, 256, 0, stream>>>((ulong2*)cnt, 25000);
  countK<<<(NE + 255) / 256, 256, 0, stream>>>(col, cnt);
  scanA<<<98, 1024, 0, stream>>>(cnt, fill, bsum);
  scanB<<<1, 64, 0, stream>>>(bsum, 98);
  scanC<<<98, 1024, 0, stream>>>(cnt, fill, bsum, off);
  scatterK<<<(NE + 255) / 256, 256, 0, stream>>>(col, fill, eid);

  convup<0><<<2500, 512, 0, stream>>>(x, ea, row, wi, b_init, nullptr,
                                      h8, sce, nullptr, nullptr, 0);
  convup<0><<<2500, 512, 0, stream>>>(x, ea, row, wi, b_init, nullptr,
                                      h8, sce, nullptr, nullptr, 256);
  for (int l = 0; l < 5; ++l) {
    zk<<<2500, 512, 0, stream>>>(h8, sce, wc + (size_t)l * 262144);
    msgk<0><<<25000, 256, 0, stream>>>(h8, sce, off, eid, msgq, scm);
    convup<1><<<2500, 512, 0, stream>>>(x, ea, row, wi, b_init, b_conv + l * 512,
                                        h8, sce, msgq, scm, 0);
    msgk<256><<<25000, 256, 0, stream>>>(h8, sce, off, eid, msgq, scm);
    convup<1><<<2500, 512, 0, stream>>>(x, ea, row, wi, b_init, b_conv + l * 512,
                                        h8, sce, msgq, scm, 256);
  }
  tker<<<25000, 256, 0, stream>>>(h8, sce, off, eid, nb8, scn);
  zero16<<<(524288 + 255) / 256, 256, 0, stream>>>((ulong2*)pooled, 524288);
  e2n<<<1563, 512, 0, stream>>>(x, nb8, scn, wex, wes, b_e2n, batch, pooled);
  cast_ph<<<(NB * 64 + 255) / 256, 256, 0, stream>>>(pooled, ph);
  ffn1<<<64, 512, 0, stream>>>(ph, wf1, b_ffn1, t1);
  final_out<<<(NB * 64 + 255) / 256, 256, 0, stream>>>(t1, W_ffn2, b_ffn2, out);
}

// Round 21
// 2423.976 us; speedup vs baseline: 1.0796x; 1.0031x over previous
//
#include <hip/hip_runtime.h>

typedef _Float16 f16;
typedef _Float16 f16x2 __attribute__((ext_vector_type(2)));
typedef _Float16 f16x4 __attribute__((ext_vector_type(4)));
typedef _Float16 f16x8 __attribute__((ext_vector_type(8)));
typedef float f32x4 __attribute__((ext_vector_type(4)));

#define NN 100000
#define NE 160000
#define NB 4096
#define HD 512

// ---- workspace layout (WS_NEEDED = 146,477,712 B < 160 MiB) ----
#define O_H8    0UL
#define O_SCE   81920000UL
#define O_SHR   87040000UL
#define O_WT    141440000UL
#define O_OFF   145437696UL
#define O_EID   145837712UL
#define WS_NEEDED 146477712UL
#define V_POOL  0UL
#define V_PH    8388608UL
#define V_T1    12582912UL
#define V_CNT   16777216UL
#define V_FILL  17177232UL
#define V_BSUM  17577248UL

__global__ void zero16(ulong2* __restrict__ p, long n) {
  long i = (long)blockIdx.x * 256 + threadIdx.x;
  if (i < n) p[i] = ulong2{0UL, 0UL};
}
__global__ void diag(float* __restrict__ out, int n, float v) {
  int i = blockIdx.x * 256 + threadIdx.x;
  if (i < n) out[i] = v;
}

__global__ void transcast(const float* __restrict__ src, f16* __restrict__ dst,
                          int Kreal, int Kpad) {
  int id = blockIdx.x * 256 + threadIdx.x;
  if (id >= 512 * Kpad) return;
  int n = id / Kpad, k = id % Kpad;
  dst[((k >> 5) * 512 + n) * 32 + (k & 31)] =
      (k < Kreal) ? (f16)src[(size_t)k * 512 + n] : (f16)0.f;
}

// ---------------- CSR by col ----------------
__global__ void countK(const int* __restrict__ col, int* __restrict__ cnt) {
  int e = blockIdx.x * 256 + threadIdx.x;
  if (e < NE) atomicAdd(&cnt[col[e]], 1);
}
__global__ __launch_bounds__(1024) void scanA(const int* __restrict__ cnt,
                                              int* __restrict__ incl, int* __restrict__ bsum) {
  __shared__ int s[1024];
  int i = blockIdx.x * 1024 + threadIdx.x;
  s[threadIdx.x] = (i < NN) ? cnt[i] : 0;
  __syncthreads();
  for (int d = 1; d < 1024; d <<= 1) {
    int t = (threadIdx.x >= d) ? s[threadIdx.x - d] : 0;
    __syncthreads();
    s[threadIdx.x] += t;
    __syncthreads();
  }
  if (i < NN) incl[i] = s[threadIdx.x];
  if (threadIdx.x == 1023) bsum[blockIdx.x] = s[1023];
}
__global__ void scanB(int* bsum, int nb) {
  if (threadIdx.x == 0 && blockIdx.x == 0) {
    int run = 0;
    for (int i = 0; i < nb; ++i) { int t = bsum[i]; bsum[i] = run; run += t; }
  }
}
__global__ __launch_bounds__(1024) void scanC(const int* __restrict__ cnt,
                                              int* __restrict__ incl_fill,
                                              const int* __restrict__ bsum,
                                              int* __restrict__ off) {
  int i = blockIdx.x * 1024 + threadIdx.x;
  if (i >= NN) return;
  int g = incl_fill[i] + bsum[blockIdx.x];
  off[i + 1] = g;
  incl_fill[i] = g - cnt[i];
  if (i == 0) off[0] = 0;
}
__global__ void scatterK(const int* __restrict__ col, int* __restrict__ fill,
                         int* __restrict__ eid) {
  int e = blockIdx.x * 256 + threadIdx.x;
  if (e >= NE) return;
  int p = atomicAdd(&fill[col[e]], 1);
  eid[p] = e;
}

// ---------------- msgk<C0>: leave-one-out message; single CSR walk with
// register cache for the first 8 edges (avg degree 1.6 -> ~all nodes).
template<int C0>
__global__ __launch_bounds__(256, 4)
void msgk(const char* __restrict__ z8, const float* __restrict__ sce,
          const int* __restrict__ off, const int* __restrict__ eid,
          char* __restrict__ msgq, float* __restrict__ scm) {
  int tid = threadIdx.x, wid = tid >> 6, lane = tid & 63;
  int n = blockIdx.x * 4 + wid;
  int s0 = off[n], s1 = off[n + 1];
  int cnt = s1 - s0;
  int g = lane >> 4;
  float a[4] = {0.f, 0.f, 0.f, 0.f};
  int ec[8]; unsigned uc[8]; float scc[8];
  #pragma unroll
  for (int i = 0; i < 8; ++i) {
    if (i < cnt) {
      int e = eid[s0 + i];
      ec[i] = e;
      scc[i] = sce[e * 8 + (C0 >> 6) + g];
      uc[i] = *reinterpret_cast<const unsigned*>(z8 + (size_t)e * 512 + C0 + lane * 4);
      #pragma unroll
      for (int b = 0; b < 4; ++b)
        a[b] += (float)(char)((uc[i] >> (8 * b)) & 0xff) * scc[i];
    }
  }
  for (int p = s0 + 8; p < s1; ++p) {
    int e = eid[p];
    float sc = sce[e * 8 + (C0 >> 6) + g];
    unsigned u = *reinterpret_cast<const unsigned*>(z8 + (size_t)e * 512 + C0 + lane * 4);
    #pragma unroll
    for (int b = 0; b < 4; ++b)
      a[b] += (float)(char)((u >> (8 * b)) & 0xff) * sc;
  }
  #pragma unroll
  for (int i = 0; i < 8; ++i) {
    if (i < cnt) {
      int f = ec[i] ^ 1;
      float mv[4]; float m = 0.f;
      #pragma unroll
      for (int b = 0; b < 4; ++b) {
        mv[b] = a[b] - (float)(char)((uc[i] >> (8 * b)) & 0xff) * scc[i];
        m = fmaxf(m, fabsf(mv[b]));
      }
      #pragma unroll
      for (int d = 1; d < 16; d <<= 1) m = fmaxf(m, __shfl_xor(m, d));
      float s2 = (m > 0.f) ? m / 127.f : 1.f;
      if ((lane & 15) == 0) scm[f * 4 + g] = s2;
      unsigned q = 0;
      #pragma unroll
      for (int b = 0; b < 4; ++b) {
        int qi = __float2int_rn(mv[b] / s2);
        qi = min(127, max(-127, qi));
        q |= ((unsigned)(unsigned char)(char)qi) << (8 * b);
      }
      *reinterpret_cast<unsigned*>(msgq + (size_t)f * 256 + lane * 4) = q;
    }
  }
  for (int p = s0 + 8; p < s1; ++p) {
    int e = eid[p];
    int f = e ^ 1;
    float sc = sce[e * 8 + (C0 >> 6) + g];
    unsigned u = *reinterpret_cast<const unsigned*>(z8 + (size_t)e * 512 + C0 + lane * 4);
    float mv[4]; float m = 0.f;
    #pragma unroll
    for (int b = 0; b < 4; ++b) {
      mv[b] = a[b] - (float)(char)((u >> (8 * b)) & 0xff) * sc;
      m = fmaxf(m, fabsf(mv[b]));
    }
    #pragma unroll
    for (int d = 1; d < 16; d <<= 1) m = fmaxf(m, __shfl_xor(m, d));
    float s2 = (m > 0.f) ? m / 127.f : 1.f;
    if ((lane & 15) == 0) scm[f * 4 + g] = s2;
    unsigned q = 0;
    #pragma unroll
    for (int b = 0; b < 4; ++b) {
      int qi = __float2int_rn(mv[b] / s2);
      qi = min(127, max(-127, qi));
      q |= ((unsigned)(unsigned char)(char)qi) << (8 * b);
    }
    *reinterpret_cast<unsigned*>(msgq + (size_t)f * 256 + lane * 4) = q;
  }
}

// ---------------- tker: s_node = segsum(h,col) ----------------
__global__ __launch_bounds__(256, 4)
void tker(const char* __restrict__ h8, const float* __restrict__ sce,
          const int* __restrict__ off, const int* __restrict__ eid,
          char* __restrict__ nb8, float* __restrict__ scn) {
  int tid = threadIdx.x, wid = tid >> 6, lane = tid & 63;
  int n = blockIdx.x * 4 + wid;
  int s0 = off[n], s1 = off[n + 1];
  int g = lane >> 3;
  float a[8] = {0.f,0.f,0.f,0.f,0.f,0.f,0.f,0.f};
  for (int p = s0; p < s1; ++p) {
    int e = eid[p];
    float sc = sce[e * 8 + g];
    uint2 u = *reinterpret_cast<const uint2*>(h8 + (size_t)e * 512 + lane * 8);
    #pragma unroll
    for (int b = 0; b < 4; ++b) {
      a[b]     += (float)((u.x >> (8 * b)) & 0xff) * sc;
      a[4 + b] += (float)((u.y >> (8 * b)) & 0xff) * sc;
    }
  }
  float m = 0.f;
  #pragma unroll
  for (int j = 0; j < 8; ++j) m = fmaxf(m, a[j]);
  #pragma unroll
  for (int d = 1; d < 8; d <<= 1) m = fmaxf(m, __shfl_xor(m, d));
  float s2 = (m > 0.f) ? m / 255.f : 1.f;
  if ((lane & 7) == 0) scn[n * 8 + g] = s2;
  unsigned lo = 0, hi = 0;
  #pragma unroll
  for (int b = 0; b < 4; ++b) {
    int q0 = __float2int_rn(a[b] / s2);     q0 = min(255, max(0, q0));
    int q1 = __float2int_rn(a[4 + b] / s2); q1 = min(255, max(0, q1));
    lo |= ((unsigned)q0) << (8 * b);
    hi |= ((unsigned)q1) << (8 * b);
  }
  *reinterpret_cast<uint2*>(nb8 + (size_t)n * 512 + lane * 8) = uint2{lo, hi};
}

// ---------------- shared GEMM helpers ----------------
static __device__ __forceinline__ void stageB512(const f16* __restrict__ wsrc,
                                                 f16* __restrict__ Bs, int tid) {
  #pragma unroll
  for (int j = 0; j < 4; ++j) {
    int u = tid * 4 + j;
    *reinterpret_cast<f16x8*>(&Bs[(u >> 2) * 40 + (u & 3) * 8]) =
        *reinterpret_cast<const f16x8*>(&wsrc[u * 8]);
  }
}
template<int AS>
static __device__ __forceinline__ void mstep8(const f16* __restrict__ As,
                                              const f16* __restrict__ Bs,
                                              f32x4 acc[2][8], int wm, int wn,
                                              int fr, int fg, int ko) {
  f16x8 af[2];
  #pragma unroll
  for (int mf = 0; mf < 2; ++mf)
    af[mf] = *reinterpret_cast<const f16x8*>(&As[(wm + mf * 16 + fr) * AS + ko + fg * 8]);
  #pragma unroll
  for (int nf = 0; nf < 8; ++nf) {
    f16x8 bf = *reinterpret_cast<const f16x8*>(&Bs[(wn + nf * 16 + fr) * 40 + fg * 8]);
    #pragma unroll
    for (int mf = 0; mf < 2; ++mf)
      acc[mf][nf] = __builtin_amdgcn_mfma_f32_16x16x32_f16(af[mf], bf, acc[mf][nf], 0, 0, 0);
  }
}

// B fragments straight from global (L2-hot weights).
static __device__ __forceinline__ void loadBfrag(const f16* __restrict__ wp,
                                                 f16x8 bf[8], int wn, int fr, int fg) {
  #pragma unroll
  for (int nf = 0; nf < 8; ++nf)
    bf[nf] = *reinterpret_cast<const f16x8*>(&wp[(size_t)(wn + nf * 16 + fr) * 32 + fg * 8]);
}

static __device__ __forceinline__ f16x2 pkfma(f16x2 a, f16x2 b, f16x2 c) {
  f16x2 r;
  asm("v_pk_fma_f16 %0, %1, %2, %3" : "=v"(r) : "v"(a), "v"(b), "v"(c));
  return r;
}

// vectorized x-row stage: 4x dwordx4 + scalar tail, write f16x4 to LDS row
static __device__ __forceinline__ void stageXrow(const float* __restrict__ xr,
                                                 f16* __restrict__ dstRow, int s) {
  #pragma unroll
  for (int j = 0; j < 4; ++j) {
    float v[4];
    __builtin_memcpy(v, xr + 4 * s + 32 * j, 16);
    f16 t4[4];
    #pragma unroll
    for (int b = 0; b < 4; ++b) t4[b] = (f16)v[b];
    *reinterpret_cast<f16x4*>(&dstRow[4 * s + 32 * j]) = *reinterpret_cast<f16x4*>(t4);
  }
  if (s < 5) dstRow[128 + s] = (f16)xr[128 + s];
}

// ---------------- zk: z = h @ W. Dequant-at-stage in 2 K-phases (proven r18) ----------------
__global__ __launch_bounds__(512, 4)
void zk(char* __restrict__ h8, float* __restrict__ sce, const f16* __restrict__ wst) {
  __shared__ f16 Af[64 * 264];        // half-K (256) f16 A tile, row stride 264
  __shared__ f16 Bs[512 * 40];
  const int tid = threadIdx.x, lane = tid & 63, wid = tid >> 6;
  const int fr = lane & 15, fg = lane >> 4;
  const int wm = (wid >> 2) * 32, wn = (wid & 3) * 128;
  const int e0 = blockIdx.x * 64;
  const int sr = tid >> 3;
  const int sc8 = tid & 7;

  auto stageA = [&](int phase) {
    const int kb = phase * 256 + sc8 * 32;
    float sa = sce[(size_t)(e0 + sr) * 8 + (kb >> 6)];
    const f16 sh = (f16)sa;
    const f16 bh = (f16)(-1024.f * sa);
    f16x2 s2; s2[0] = sh; s2[1] = sh;
    f16x2 b2; b2[0] = bh; b2[1] = bh;
    const int4* src = reinterpret_cast<const int4*>(h8 + (size_t)(e0 + sr) * 512 + kb);
    f16* dst = &Af[sr * 264 + sc8 * 32];
    #pragma unroll
    for (int j = 0; j < 2; ++j) {
      int4 w = src[j];
      unsigned vv[4] = {(unsigned)w.x, (unsigned)w.y, (unsigned)w.z, (unsigned)w.w};
      #pragma unroll
      for (int q = 0; q < 2; ++q) {
        unsigned p0 = __builtin_amdgcn_perm(0x64646464u, vv[2*q],     0x05010400u);
        unsigned p1 = __builtin_amdgcn_perm(0x64646464u, vv[2*q],     0x05030402u);
        unsigned p2 = __builtin_amdgcn_perm(0x64646464u, vv[2*q + 1], 0x05010400u);
        unsigned p3 = __builtin_amdgcn_perm(0x64646464u, vv[2*q + 1], 0x05030402u);
        uint4 o;
        o.x = __builtin_bit_cast(unsigned, pkfma(__builtin_bit_cast(f16x2, p0), s2, b2));
        o.y = __builtin_bit_cast(unsigned, pkfma(__builtin_bit_cast(f16x2, p1), s2, b2));
        o.z = __builtin_bit_cast(unsigned, pkfma(__builtin_bit_cast(f16x2, p2), s2, b2));
        o.w = __builtin_bit_cast(unsigned, pkfma(__builtin_bit_cast(f16x2, p3), s2, b2));
        *reinterpret_cast<uint4*>(dst + j * 16 + q * 8) = o;
      }
    }
  };

  stageA(0);
  f32x4 acc[2][8] = {};
  for (int step = 0; step < 16; ++step) {
    if (step == 8) stageA(1);
    stageB512(wst + (size_t)step * 16384, Bs, tid);
    __syncthreads();
    const int ko = (step & 7) * 32;
    f16x8 af[2];
    #pragma unroll
    for (int mf = 0; mf < 2; ++mf)
      af[mf] = *reinterpret_cast<const f16x8*>(&Af[(wm + mf * 16 + fr) * 264 + ko + fg * 8]);
    #pragma unroll
    for (int nf = 0; nf < 8; ++nf) {
      f16x8 bf = *reinterpret_cast<const f16x8*>(&Bs[(wn + nf * 16 + fr) * 40 + fg * 8]);
      #pragma unroll
      for (int mf = 0; mf < 2; ++mf)
        acc[mf][nf] = __builtin_amdgcn_mfma_f32_16x16x32_f16(af[mf], bf, acc[mf][nf], 0, 0, 0);
    }
    __syncthreads();
  }
  float scA[2][4], scB[2][4];
  #pragma unroll
  for (int mf = 0; mf < 2; ++mf)
    #pragma unroll
    for (int i = 0; i < 4; ++i) {
      float mA = 0.f, mB = 0.f;
      #pragma unroll
      for (int nf = 0; nf < 4; ++nf) mA = fmaxf(mA, fabsf(acc[mf][nf][i]));
      #pragma unroll
      for (int nf = 4; nf < 8; ++nf) mB = fmaxf(mB, fabsf(acc[mf][nf][i]));
      #pragma unroll
      for (int d = 1; d < 16; d <<= 1) {
        mA = fmaxf(mA, __shfl_xor(mA, d));
        mB = fmaxf(mB, __shfl_xor(mB, d));
      }
      scA[mf][i] = (mA > 0.f) ? mA / 127.f : 1.f;
      scB[mf][i] = (mB > 0.f) ? mB / 127.f : 1.f;
      if (fr == 0) {
        int r = wm + mf * 16 + fg * 4 + i;
        sce[(size_t)(e0 + r) * 8 + (wn >> 6)]     = scA[mf][i];
        sce[(size_t)(e0 + r) * 8 + (wn >> 6) + 1] = scB[mf][i];
      }
    }
  char* q8 = (char*)&Bs[0];
  #pragma unroll
  for (int mf = 0; mf < 2; ++mf)
    #pragma unroll
    for (int nf = 0; nf < 8; ++nf) {
      int c = wn + nf * 16 + fr;
      #pragma unroll
      for (int i = 0; i < 4; ++i) {
        int r = wm + mf * 16 + fg * 4 + i;
        float s = (nf < 4) ? scA[mf][i] : scB[mf][i];
        int q = __float2int_rn(acc[mf][nf][i] / s);
        q8[r * 512 + c] = (char)min(127, max(-127, q));
      }
    }
  __syncthreads();
  { int4* dst = reinterpret_cast<int4*>(h8 + (size_t)e0 * 512);
    const int4* s4 = reinterpret_cast<const int4*>(q8);
    #pragma unroll
    for (int j = 0; j < 4; ++j) dst[tid * 4 + j] = s4[tid * 4 + j]; }
}

// ---------------- convup: half-width; B direct from L2 (e2n pattern),
// barrier-free 5-step loop, no Bs dbuf -> LDS 38.9K -> 4 blocks/CU.
template<int MODE>
__global__ __launch_bounds__(512, 4)
void convup(const float* __restrict__ x, const float* __restrict__ ea,
            const int* __restrict__ row, const f16* __restrict__ wi,
            const float* __restrict__ bi, const float* __restrict__ bc,
            char* __restrict__ h8, float* __restrict__ sce,
            const char* __restrict__ msgq, const float* __restrict__ scm,
            int c0) {
  __shared__ f16 As[64 * 168];
  __shared__ char m8s[64 * 256];
  __shared__ float scmL[64 * 4];
  const int tid = threadIdx.x, lane = tid & 63, wid = tid >> 6;
  const int fr = lane & 15, fg = lane >> 4;
  const int wm = (wid >> 2) * 32, wn = (wid & 3) * 64;
  const int e0 = blockIdx.x * 64;

  { // stage A1 = [x[row]|ea] pad->160 (vectorized); msg tile for MODE 1
    int r = tid >> 3, s = tid & 7;
    int rid = row[e0 + r];
    stageXrow(x + (size_t)rid * 133, &As[r * 168], s);
    if (s < 7) {
      float2 e2 = *reinterpret_cast<const float2*>(ea + (size_t)(e0 + r) * 14 + 2 * s);
      As[r * 168 + 133 + 2 * s]     = (f16)e2.x;
      As[r * 168 + 133 + 2 * s + 1] = (f16)e2.y;
    }
    for (int k = 147 + s; k < 160; k += 8) As[r * 168 + k] = (f16)0.f;
    if (MODE == 1) {
      const int4* ms = reinterpret_cast<const int4*>(msgq + (size_t)(e0 + r) * 256 + s * 32);
      int4* md = reinterpret_cast<int4*>(m8s + r * 256 + s * 32);
      md[0] = ms[0]; md[1] = ms[1];
      if (s < 4) scmL[r * 4 + s] = scm[(size_t)(e0 + r) * 4 + s];
    }
  }
  __syncthreads();
  f32x4 acc[2][4] = {};
  #pragma unroll
  for (int step = 0; step < 5; ++step) {
    // B fragments direct from L2-resident wi (same [k/32][n][k&31] layout/values
    // as the old staged path)
    f16x8 bf[4];
    const f16* wsrc = wi + (size_t)step * 16384;
    #pragma unroll
    for (int nf = 0; nf < 4; ++nf)
      bf[nf] = *reinterpret_cast<const f16x8*>(
          &wsrc[(size_t)(c0 + wn + nf * 16 + fr) * 32 + fg * 8]);
    f16x8 af[2];
    #pragma unroll
    for (int mf = 0; mf < 2; ++mf)
      af[mf] = *reinterpret_cast<const f16x8*>(&As[(wm + mf * 16 + fr) * 168 + step * 32 + fg * 8]);
    #pragma unroll
    for (int nf = 0; nf < 4; ++nf)
      #pragma unroll
      for (int mf = 0; mf < 2; ++mf)
        acc[mf][nf] = __builtin_amdgcn_mfma_f32_16x16x32_f16(af[mf], bf[nf], acc[mf][nf], 0, 0, 0);
  }
  // epilogue: h0 = relu(gemm+bi); MODE1: h' = relu(h0 + bc + msg)
  #pragma unroll
  for (int nf = 0; nf < 4; ++nf) {
    int cl = wn + nf * 16 + fr;
    int cg = c0 + cl;
    float bi_ = bi[cg];
    float bc_ = (MODE == 1) ? bc[cg] : 0.f;
    #pragma unroll
    for (int mf = 0; mf < 2; ++mf)
      #pragma unroll
      for (int i = 0; i < 4; ++i) {
        int r = wm + mf * 16 + fg * 4 + i;
        float v = fmaxf(acc[mf][nf][i] + bi_, 0.f);
        if (MODE == 1) {
          float mv = (float)(char)m8s[r * 256 + cl] * scmL[r * 4 + (cl >> 6)];
          v = fmaxf(v + bc_ + mv, 0.f);
        }
        acc[mf][nf][i] = v;
      }
  }
  float sc_[2][4];
  #pragma unroll
  for (int mf = 0; mf < 2; ++mf)
    #pragma unroll
    for (int i = 0; i < 4; ++i) {
      float m = 0.f;
      #pragma unroll
      for (int nf = 0; nf < 4; ++nf) m = fmaxf(m, acc[mf][nf][i]);
      #pragma unroll
      for (int d = 1; d < 16; d <<= 1) m = fmaxf(m, __shfl_xor(m, d));
      sc_[mf][i] = (m > 0.f) ? m / 255.f : 1.f;
      if (fr == 0)
        sce[(size_t)(e0 + wm + mf * 16 + fg * 4 + i) * 8 + (c0 >> 6) + (wn >> 6)] = sc_[mf][i];
    }
  __syncthreads();   // all msg reads done before reusing m8s as bounce
  #pragma unroll
  for (int mf = 0; mf < 2; ++mf)
    #pragma unroll
    for (int nf = 0; nf < 4; ++nf) {
      int cl = wn + nf * 16 + fr;
      #pragma unroll
      for (int i = 0; i < 4; ++i) {
        int r = wm + mf * 16 + fg * 4 + i;
        int q = __float2int_rn(acc[mf][nf][i] / sc_[mf][i]);
        m8s[r * 256 + cl] = (char)(unsigned char)min(255, max(0, q));
      }
    }
  __syncthreads();
  { int r = tid >> 3, s = tid & 7;
    int4* dst = reinterpret_cast<int4*>(h8 + (size_t)(e0 + r) * 512 + c0 + s * 32);
    const int4* sp = reinterpret_cast<const int4*>(m8s + r * 256 + s * 32);
    dst[0] = sp[0]; dst[1] = sp[1]; }
}

// ---------------- e2n: B direct from L2, barrier-free GEMMs; vectorized gather ----------------
__global__ __launch_bounds__(512, 4)
void e2n(const float* __restrict__ x, const char* __restrict__ nb8,
         const float* __restrict__ scn, const f16* __restrict__ wex,
         const f16* __restrict__ wes, const float* __restrict__ be,
         const int* __restrict__ batch, float* __restrict__ pooled) {
  __shared__ f16 As[64 * 520];
  __shared__ int bat[64];
  const int tid = threadIdx.x, lane = tid & 63, wid = tid >> 6;
  const int fr = lane & 15, fg = lane >> 4;
  const int wm = (wid >> 2) * 32, wn = (wid & 3) * 128;
  const int n0 = blockIdx.x * 64;
  if (tid < 64) { int nn = n0 + tid; bat[tid] = (nn < NN) ? batch[nn] : 0; }
  { // x part, stride 168 (vectorized)
    int r = tid >> 3, s = tid & 7;
    int nid = min(n0 + r, NN - 1);
    stageXrow(x + (size_t)nid * 133, &As[r * 168], s);
    for (int k = 133 + s; k < 160; k += 8) As[r * 168 + k] = (f16)0.f;
  }
  __syncthreads();
  f32x4 acc[2][8] = {};
  for (int step = 0; step < 5; ++step) {
    f16x8 bf[8];
    loadBfrag(wex + (size_t)step * 16384, bf, wn, fr, fg);
    f16x8 af[2];
    #pragma unroll
    for (int mf = 0; mf < 2; ++mf)
      af[mf] = *reinterpret_cast<const f16x8*>(&As[(wm + mf * 16 + fr) * 168 + step * 32 + fg * 8]);
    #pragma unroll
    for (int nf = 0; nf < 8; ++nf)
      #pragma unroll
      for (int mf = 0; mf < 2; ++mf)
        acc[mf][nf] = __builtin_amdgcn_mfma_f32_16x16x32_f16(af[mf], bf[nf], acc[mf][nf], 0, 0, 0);
  }
  __syncthreads();
  { // re-stage As with dequantized s_node (u8 groupwise), stride 520
    int r = tid >> 3, s = tid & 7, kb = s * 64;
    int nid = min(n0 + r, NN - 1);
    float sc = scn[(size_t)nid * 8 + s];
    const int4* src = reinterpret_cast<const int4*>(nb8 + (size_t)nid * 512 + kb);
    #pragma unroll
    for (int j = 0; j < 4; ++j) {
      int4 w = src[j];
      unsigned vv[4] = {(unsigned)w.x, (unsigned)w.y, (unsigned)w.z, (unsigned)w.w};
      f16 tmp[16];
      #pragma unroll
      for (int q = 0; q < 4; ++q)
        #pragma unroll
        for (int b = 0; b < 4; ++b)
          tmp[q * 4 + b] = (f16)((float)((vv[q] >> (8 * b)) & 0xff) * sc);
      *reinterpret_cast<f16x8*>(&As[r * 520 + kb + j * 16])     = *reinterpret_cast<f16x8*>(&tmp[0]);
      *reinterpret_cast<f16x8*>(&As[r * 520 + kb + j * 16 + 8]) = *reinterpret_cast<f16x8*>(&tmp[8]);
    }
  }
  __syncthreads();
  for (int step = 0; step < 16; ++step) {
    f16x8 bf[8];
    loadBfrag(wes + (size_t)step * 16384, bf, wn, fr, fg);
    f16x8 af[2];
    #pragma unroll
    for (int mf = 0; mf < 2; ++mf)
      af[mf] = *reinterpret_cast<const f16x8*>(&As[(wm + mf * 16 + fr) * 520 + step * 32 + fg * 8]);
    #pragma unroll
    for (int nf = 0; nf < 8; ++nf)
      #pragma unroll
      for (int mf = 0; mf < 2; ++mf)
        acc[mf][nf] = __builtin_amdgcn_mfma_f32_16x16x32_f16(af[mf], bf[nf], acc[mf][nf], 0, 0, 0);
  }
  __syncthreads();
  // epilogue 1: hn -> As (f16 bounce, stride 520)
  #pragma unroll
  for (int nf = 0; nf < 8; ++nf) {
    int c = wn + nf * 16 + fr;
    float b_ = be[c];
    #pragma unroll
    for (int mf = 0; mf < 2; ++mf)
      #pragma unroll
      for (int i = 0; i < 4; ++i) {
        int rl = wm + mf * 16 + fg * 4 + i;
        As[rl * 520 + c] = (f16)fmaxf(acc[mf][nf][i] + b_, 0.f);
      }
  }
  __syncthreads();
  // epilogue 2: per-column segmented run-accumulate over sorted batch ids
  {
    const int c = tid;
    float s = 0.f;
    int pb = bat[0];
    #pragma unroll 1
    for (int r = 0; r < 64; ++r) {
      if (n0 + r >= NN) break;
      int b = bat[r];
      if (b != pb) {
        atomicAdd(&pooled[(size_t)pb * 512 + c], s);
        s = 0.f; pb = b;
      }
      s += (float)As[r * 520 + c];
    }
    atomicAdd(&pooled[(size_t)pb * 512 + c], s);
  }
}

// ---------------- ffn1: double-buffered B ----------------
__global__ __launch_bounds__(512, 1)
void ffn1(const f16* __restrict__ ph, const f16* __restrict__ wf,
          const float* __restrict__ b1, f16* __restrict__ t1) {
  __shared__ f16 As[64 * 520];
  __shared__ f16 Bs[2][512 * 40];
  const int tid = threadIdx.x, lane = tid & 63, wid = tid >> 6;
  const int fr = lane & 15, fg = lane >> 4;
  const int wm = (wid >> 2) * 32, wn = (wid & 3) * 128;
  const int n0 = blockIdx.x * 64;
  { int r = tid >> 3, hs = (tid & 7) * 64;
    #pragma unroll
    for (int j = 0; j < 8; ++j)
      *reinterpret_cast<f16x8*>(&As[r * 520 + hs + j * 8]) =
          *reinterpret_cast<const f16x8*>(&ph[(size_t)(n0 + r) * 512 + hs + j * 8]); }
  stageB512(wf, Bs[0], tid);
  __syncthreads();
  f32x4 acc[2][8] = {};
  for (int step = 0; step < 16; ++step) {
    const int cur = step & 1;
    f16x8 pf[4];
    if (step < 15) {
      const f16* wsrc = wf + (size_t)(step + 1) * 16384;
      #pragma unroll
      for (int j = 0; j < 4; ++j)
        pf[j] = *reinterpret_cast<const f16x8*>(&wsrc[(size_t)(tid * 4 + j) * 8]);
    }
    mstep8<520>(As, Bs[cur], acc, wm, wn, fr, fg, step * 32);
    if (step < 15) {
      #pragma unroll
      for (int j = 0; j < 4; ++j) {
        int u = tid * 4 + j;
        *reinterpret_cast<f16x8*>(&Bs[cur ^ 1][(u >> 2) * 40 + (u & 3) * 8]) = pf[j];
      }
    }
    __syncthreads();
  }
  f16* q16 = As;
  #pragma unroll
  for (int nf = 0; nf < 8; ++nf) {
    int c = wn + nf * 16 + fr;
    float b_ = b1[c];
    #pragma unroll
    for (int mf = 0; mf < 2; ++mf)
      #pragma unroll
      for (int i = 0; i < 4; ++i) {
        int r = wm + mf * 16 + fg * 4 + i;
        q16[r * 512 + c] = (f16)fmaxf(acc[mf][nf][i] + b_, 0.f);
      }
  }
  __syncthreads();
  #pragma unroll
  for (int j = 0; j < 8; ++j)
    *reinterpret_cast<f16x8*>(&t1[(size_t)n0 * 512 + tid * 64 + j * 8]) =
        *reinterpret_cast<const f16x8*>(&q16[tid * 64 + j * 8]);
}

__global__ void cast_ph(const float* __restrict__ pooled, f16* __restrict__ ph) {
  int id = blockIdx.x * 256 + threadIdx.x;
  if (id >= NB * 64) return;
  int k = id * 8;
  f16 v[8];
  #pragma unroll
  for (int i = 0; i < 8; ++i) v[i] = (f16)pooled[k + i];
  *reinterpret_cast<f16x8*>(&ph[k]) = *reinterpret_cast<f16x8*>(&v[0]);
}

__global__ void final_out(const f16* __restrict__ t, const float* __restrict__ W2,
                          const float* __restrict__ b2, float* __restrict__ out) {
  int id = blockIdx.x * 256 + threadIdx.x;
  if (id >= NB * 64) return;
  int b = id >> 6, lane = id & 63;
  f16x8 v = *reinterpret_cast<const f16x8*>(&t[(size_t)b * HD + lane * 8]);
  float s = 0.f;
  #pragma unroll
  for (int i = 0; i < 8; ++i) s += (float)v[i] * W2[lane * 8 + i];
  #pragma unroll
  for (int o = 32; o > 0; o >>= 1) s += __shfl_down(s, o);
  if (lane == 0) out[b] = s + b2[0];
}

extern "C" void kernel_launch(void* const* d_in, const int* in_sizes, int n_in,
                              void* d_out, int out_size, void* d_ws, size_t ws_size,
                              hipStream_t stream) {
  const float* x      = (const float*)d_in[0];
  const float* ea     = (const float*)d_in[1];
  const int*   ei     = (const int*)d_in[2];
  const int*   batch  = (const int*)d_in[3];
  const float* W_init = (const float*)d_in[4];
  const float* b_init = (const float*)d_in[5];
  const float* W_conv = (const float*)d_in[6];
  const float* b_conv = (const float*)d_in[7];
  const float* W_e2n  = (const float*)d_in[8];
  const float* b_e2n  = (const float*)d_in[9];
  const float* W_ffn1 = (const float*)d_in[10];
  const float* b_ffn1 = (const float*)d_in[11];
  const float* W_ffn2 = (const float*)d_in[12];
  const float* b_ffn2 = (const float*)d_in[13];
  const int* row = ei;
  const int* col = ei + NE;
  float* out = (float*)d_out;

  if (ws_size < WS_NEEDED) {
    diag<<<(out_size + 255) / 256, 256, 0, stream>>>(out, out_size, (float)(ws_size >> 20));
    return;
  }

  char* ws = (char*)d_ws;
  char*  h8   = ws + O_H8;
  float* sce  = (float*)(ws + O_SCE);
  char*  msgq = ws + O_SHR;
  float* scm  = (float*)(ws + O_SHR + 40960000UL);
  char*  nb8  = ws + O_SHR;
  float* scn  = (float*)(ws + O_SHR + 51200000UL);
  f16*   wt   = (f16*)(ws + O_WT);
  int*   off  = (int*)(ws + O_OFF);
  int*   eid  = (int*)(ws + O_EID);
  float* pooled = (float*)(ws + V_POOL);
  f16*   ph   = (f16*)(ws + V_PH);
  f16*   t1   = (f16*)(ws + V_T1);
  int*   cnt  = (int*)(ws + V_CNT);
  int*   fill = (int*)(ws + V_FILL);
  int*   bsum = (int*)(ws + V_BSUM);

  f16* wi  = wt;
  f16* wc  = wi + 160 * 512;
  f16* wex = wc + 5 * 512 * 512;
  f16* wes = wex + 160 * 512;
  f16* wf1 = wes + 512 * 512;

  transcast<<<(512 * 160 + 255) / 256, 256, 0, stream>>>(W_init, wi, 147, 160);
  for (int l = 0; l < 5; ++l)
    transcast<<<(512 * 512 + 255) / 256, 256, 0, stream>>>(
        W_conv + (size_t)l * 262144, wc + (size_t)l * 262144, 512, 512);
  transcast<<<(512 * 160 + 255) / 256, 256, 0, stream>>>(W_e2n, wex, 133, 160);
  transcast<<<(512 * 512 + 255) / 256, 256, 0, stream>>>(W_e2n + 133 * 512, wes, 512, 512);
  transcast<<<(512 * 512 + 255) / 256, 256, 0, stream>>>(W_ffn1, wf1, 512, 512);

  zero16<<<(25000 + 255) / 256, 256, 0, stream>>>((ulong2*)cnt, 25000);
  countK<<<(NE + 255) / 256, 256, 0, stream>>>(col, cnt);
  scanA<<<98, 1024, 0, stream>>>(cnt, fill, bsum);
  scanB<<<1, 64, 0, stream>>>(bsum, 98);
  scanC<<<98, 1024, 0, stream>>>(cnt, fill, bsum, off);
  scatterK<<<(NE + 255) / 256, 256, 0, stream>>>(col, fill, eid);

  convup<0><<<2500, 512, 0, stream>>>(x, ea, row, wi, b_init, nullptr,
                                      h8, sce, nullptr, nullptr, 0);
  convup<0><<<2500, 512, 0, stream>>>(x, ea, row, wi, b_init, nullptr,
                                      h8, sce, nullptr, nullptr, 256);
  for (int l = 0; l < 5; ++l) {
    zk<<<2500, 512, 0, stream>>>(h8, sce, wc + (size_t)l * 262144);
    msgk<0><<<25000, 256, 0, stream>>>(h8, sce, off, eid, msgq, scm);
    convup<1><<<2500, 512, 0, stream>>>(x, ea, row, wi, b_init, b_conv + l * 512,
                                        h8, sce, msgq, scm, 0);
    msgk<256><<<25000, 256, 0, stream>>>(h8, sce, off, eid, msgq, scm);
    convup<1><<<2500, 512, 0, stream>>>(x, ea, row, wi, b_init, b_conv + l * 512,
                                        h8, sce, msgq, scm, 256);
  }
  tker<<<25000, 256, 0, stream>>>(h8, sce, off, eid, nb8, scn);
  zero16<<<(524288 + 255) / 256, 256, 0, stream>>>((ulong2*)pooled, 524288);
  e2n<<<1563, 512, 0, stream>>>(x, nb8, scn, wex, wes, b_e2n, batch, pooled);
  cast_ph<<<(NB * 64 + 255) / 256, 256, 0, stream>>>(pooled, ph);
  ffn1<<<64, 512, 0, stream>>>(ph, wf1, b_ffn1, t1);
  final_out<<<(NB * 64 + 255) / 256, 256, 0, stream>>>(t1, W_ffn2, b_ffn2, out);
}

// Round 22
// 2401.665 us; speedup vs baseline: 1.0896x; 1.0093x over previous
//
#include <hip/hip_runtime.h>

typedef _Float16 f16;
typedef _Float16 f16x2 __attribute__((ext_vector_type(2)));
typedef _Float16 f16x4 __attribute__((ext_vector_type(4)));
typedef _Float16 f16x8 __attribute__((ext_vector_type(8)));
typedef float f32x4 __attribute__((ext_vector_type(4)));

#define NN 100000
#define NE 160000
#define NB 4096
#define HD 512

// ---- workspace layout (WS_NEEDED = 146,477,712 B < 160 MiB) ----
#define O_H8    0UL
#define O_SCE   81920000UL
#define O_SHR   87040000UL
#define O_WT    141440000UL
#define O_OFF   145437696UL
#define O_EID   145837712UL
#define WS_NEEDED 146477712UL
#define V_POOL  0UL
#define V_PH    8388608UL
#define V_T1    12582912UL
#define V_CNT   16777216UL
#define V_FILL  17177232UL
#define V_BSUM  17577248UL

__global__ void zero16(ulong2* __restrict__ p, long n) {
  long i = (long)blockIdx.x * 256 + threadIdx.x;
  if (i < n) p[i] = ulong2{0UL, 0UL};
}
__global__ void diag(float* __restrict__ out, int n, float v) {
  int i = blockIdx.x * 256 + threadIdx.x;
  if (i < n) out[i] = v;
}

// all 8 weight conversions in ONE launch (region-dispatch by flat id)
__global__ void transcast_all(const float* __restrict__ W_init,
                              const float* __restrict__ W_conv,
                              const float* __restrict__ W_e2n,
                              const float* __restrict__ W_ffn1,
                              f16* __restrict__ wt) {
  long id = (long)blockIdx.x * 256 + threadIdx.x;
  const float* src; f16* dst; int Kreal, Kpad; long loc;
  if (id < 81920)        { loc = id;            src = W_init;           dst = wt;           Kreal = 147; Kpad = 160;
    int n = (int)(loc / 160), k = (int)(loc % 160);
    dst[((k >> 5) * 512 + n) * 32 + (k & 31)] = (k < Kreal) ? (f16)src[(size_t)k * 512 + n] : (f16)0.f;
  } else if (id < 1392640) { long t = id - 81920; int l = (int)(t >> 18); loc = t & 262143;
    src = W_conv + (size_t)l * 262144; dst = wt + 81920 + (size_t)l * 262144;
    int n = (int)(loc / 512), k = (int)(loc % 512);
    dst[((k >> 5) * 512 + n) * 32 + (k & 31)] = (f16)src[(size_t)k * 512 + n];
  } else if (id < 1474560) { loc = id - 1392640; src = W_e2n;            dst = wt + 1392640; Kreal = 133; Kpad = 160;
    int n = (int)(loc / 160), k = (int)(loc % 160);
    dst[((k >> 5) * 512 + n) * 32 + (k & 31)] = (k < Kreal) ? (f16)src[(size_t)k * 512 + n] : (f16)0.f;
  } else if (id < 1736704) { loc = id - 1474560; src = W_e2n + 133 * 512; dst = wt + 1474560;
    int n = (int)(loc / 512), k = (int)(loc % 512);
    dst[((k >> 5) * 512 + n) * 32 + (k & 31)] = (f16)src[(size_t)k * 512 + n];
  } else if (id < 1998848) { loc = id - 1736704; src = W_ffn1;           dst = wt + 1736704;
    int n = (int)(loc / 512), k = (int)(loc % 512);
    dst[((k >> 5) * 512 + n) * 32 + (k & 31)] = (f16)src[(size_t)k * 512 + n];
  }
}

// ---------------- CSR by col ----------------
__global__ void countK(const int* __restrict__ col, int* __restrict__ cnt) {
  int e = blockIdx.x * 256 + threadIdx.x;
  if (e < NE) atomicAdd(&cnt[col[e]], 1);
}
__global__ __launch_bounds__(1024) void scanA(const int* __restrict__ cnt,
                                              int* __restrict__ incl, int* __restrict__ bsum) {
  __shared__ int s[1024];
  int i = blockIdx.x * 1024 + threadIdx.x;
  s[threadIdx.x] = (i < NN) ? cnt[i] : 0;
  __syncthreads();
  for (int d = 1; d < 1024; d <<= 1) {
    int t = (threadIdx.x >= d) ? s[threadIdx.x - d] : 0;
    __syncthreads();
    s[threadIdx.x] += t;
    __syncthreads();
  }
  if (i < NN) incl[i] = s[threadIdx.x];
  if (threadIdx.x == 1023) bsum[blockIdx.x] = s[1023];
}
__global__ void scanB(int* bsum, int nb) {
  if (threadIdx.x == 0 && blockIdx.x == 0) {
    int run = 0;
    for (int i = 0; i < nb; ++i) { int t = bsum[i]; bsum[i] = run; run += t; }
  }
}
__global__ __launch_bounds__(1024) void scanC(const int* __restrict__ cnt,
                                              int* __restrict__ incl_fill,
                                              const int* __restrict__ bsum,
                                              int* __restrict__ off) {
  int i = blockIdx.x * 1024 + threadIdx.x;
  if (i >= NN) return;
  int g = incl_fill[i] + bsum[blockIdx.x];
  off[i + 1] = g;
  incl_fill[i] = g - cnt[i];
  if (i == 0) off[0] = 0;
}
__global__ void scatterK(const int* __restrict__ col, int* __restrict__ fill,
                         int* __restrict__ eid) {
  int e = blockIdx.x * 256 + threadIdx.x;
  if (e >= NE) return;
  int p = atomicAdd(&fill[col[e]], 1);
  eid[p] = e;
}

// ---------------- msgk<C0>: leave-one-out message; single CSR walk with
// register cache for the first 8 edges (avg degree 1.6 -> ~all nodes).
template<int C0>
__global__ __launch_bounds__(256, 4)
void msgk(const char* __restrict__ z8, const float* __restrict__ sce,
          const int* __restrict__ off, const int* __restrict__ eid,
          char* __restrict__ msgq, float* __restrict__ scm) {
  int tid = threadIdx.x, wid = tid >> 6, lane = tid & 63;
  int n = blockIdx.x * 4 + wid;
  int s0 = off[n], s1 = off[n + 1];
  int cnt = s1 - s0;
  int g = lane >> 4;
  float a[4] = {0.f, 0.f, 0.f, 0.f};
  int ec[8]; unsigned uc[8]; float scc[8];
  #pragma unroll
  for (int i = 0; i < 8; ++i) {
    if (i < cnt) {
      int e = eid[s0 + i];
      ec[i] = e;
      scc[i] = sce[e * 8 + (C0 >> 6) + g];
      uc[i] = *reinterpret_cast<const unsigned*>(z8 + (size_t)e * 512 + C0 + lane * 4);
      #pragma unroll
      for (int b = 0; b < 4; ++b)
        a[b] += (float)(char)((uc[i] >> (8 * b)) & 0xff) * scc[i];
    }
  }
  for (int p = s0 + 8; p < s1; ++p) {
    int e = eid[p];
    float sc = sce[e * 8 + (C0 >> 6) + g];
    unsigned u = *reinterpret_cast<const unsigned*>(z8 + (size_t)e * 512 + C0 + lane * 4);
    #pragma unroll
    for (int b = 0; b < 4; ++b)
      a[b] += (float)(char)((u >> (8 * b)) & 0xff) * sc;
  }
  #pragma unroll
  for (int i = 0; i < 8; ++i) {
    if (i < cnt) {
      int f = ec[i] ^ 1;
      float mv[4]; float m = 0.f;
      #pragma unroll
      for (int b = 0; b < 4; ++b) {
        mv[b] = a[b] - (float)(char)((uc[i] >> (8 * b)) & 0xff) * scc[i];
        m = fmaxf(m, fabsf(mv[b]));
      }
      #pragma unroll
      for (int d = 1; d < 16; d <<= 1) m = fmaxf(m, __shfl_xor(m, d));
      float s2 = (m > 0.f) ? m / 127.f : 1.f;
      if ((lane & 15) == 0) scm[f * 4 + g] = s2;
      unsigned q = 0;
      #pragma unroll
      for (int b = 0; b < 4; ++b) {
        int qi = __float2int_rn(mv[b] / s2);
        qi = min(127, max(-127, qi));
        q |= ((unsigned)(unsigned char)(char)qi) << (8 * b);
      }
      *reinterpret_cast<unsigned*>(msgq + (size_t)f * 256 + lane * 4) = q;
    }
  }
  for (int p = s0 + 8; p < s1; ++p) {
    int e = eid[p];
    int f = e ^ 1;
    float sc = sce[e * 8 + (C0 >> 6) + g];
    unsigned u = *reinterpret_cast<const unsigned*>(z8 + (size_t)e * 512 + C0 + lane * 4);
    float mv[4]; float m = 0.f;
    #pragma unroll
    for (int b = 0; b < 4; ++b) {
      mv[b] = a[b] - (float)(char)((u >> (8 * b)) & 0xff) * sc;
      m = fmaxf(m, fabsf(mv[b]));
    }
    #pragma unroll
    for (int d = 1; d < 16; d <<= 1) m = fmaxf(m, __shfl_xor(m, d));
    float s2 = (m > 0.f) ? m / 127.f : 1.f;
    if ((lane & 15) == 0) scm[f * 4 + g] = s2;
    unsigned q = 0;
    #pragma unroll
    for (int b = 0; b < 4; ++b) {
      int qi = __float2int_rn(mv[b] / s2);
      qi = min(127, max(-127, qi));
      q |= ((unsigned)(unsigned char)(char)qi) << (8 * b);
    }
    *reinterpret_cast<unsigned*>(msgq + (size_t)f * 256 + lane * 4) = q;
  }
}

// ---------------- tker: s_node = segsum(h,col) ----------------
__global__ __launch_bounds__(256, 4)
void tker(const char* __restrict__ h8, const float* __restrict__ sce,
          const int* __restrict__ off, const int* __restrict__ eid,
          char* __restrict__ nb8, float* __restrict__ scn) {
  int tid = threadIdx.x, wid = tid >> 6, lane = tid & 63;
  int n = blockIdx.x * 4 + wid;
  int s0 = off[n], s1 = off[n + 1];
  int g = lane >> 3;
  float a[8] = {0.f,0.f,0.f,0.f,0.f,0.f,0.f,0.f};
  for (int p = s0; p < s1; ++p) {
    int e = eid[p];
    float sc = sce[e * 8 + g];
    uint2 u = *reinterpret_cast<const uint2*>(h8 + (size_t)e * 512 + lane * 8);
    #pragma unroll
    for (int b = 0; b < 4; ++b) {
      a[b]     += (float)((u.x >> (8 * b)) & 0xff) * sc;
      a[4 + b] += (float)((u.y >> (8 * b)) & 0xff) * sc;
    }
  }
  float m = 0.f;
  #pragma unroll
  for (int j = 0; j < 8; ++j) m = fmaxf(m, a[j]);
  #pragma unroll
  for (int d = 1; d < 8; d <<= 1) m = fmaxf(m, __shfl_xor(m, d));
  float s2 = (m > 0.f) ? m / 255.f : 1.f;
  if ((lane & 7) == 0) scn[n * 8 + g] = s2;
  unsigned lo = 0, hi = 0;
  #pragma unroll
  for (int b = 0; b < 4; ++b) {
    int q0 = __float2int_rn(a[b] / s2);     q0 = min(255, max(0, q0));
    int q1 = __float2int_rn(a[4 + b] / s2); q1 = min(255, max(0, q1));
    lo |= ((unsigned)q0) << (8 * b);
    hi |= ((unsigned)q1) << (8 * b);
  }
  *reinterpret_cast<uint2*>(nb8 + (size_t)n * 512 + lane * 8) = uint2{lo, hi};
}

// ---------------- shared GEMM helpers ----------------
static __device__ __forceinline__ void stageB512(const f16* __restrict__ wsrc,
                                                 f16* __restrict__ Bs, int tid) {
  #pragma unroll
  for (int j = 0; j < 4; ++j) {
    int u = tid * 4 + j;
    *reinterpret_cast<f16x8*>(&Bs[(u >> 2) * 40 + (u & 3) * 8]) =
        *reinterpret_cast<const f16x8*>(&wsrc[u * 8]);
  }
}

// B fragments straight from global (L2-hot weights).
static __device__ __forceinline__ void loadBfrag(const f16* __restrict__ wp,
                                                 f16x8 bf[8], int wn, int fr, int fg) {
  #pragma unroll
  for (int nf = 0; nf < 8; ++nf)
    bf[nf] = *reinterpret_cast<const f16x8*>(&wp[(size_t)(wn + nf * 16 + fr) * 32 + fg * 8]);
}

static __device__ __forceinline__ f16x2 pkfma(f16x2 a, f16x2 b, f16x2 c) {
  f16x2 r;
  asm("v_pk_fma_f16 %0, %1, %2, %3" : "=v"(r) : "v"(a), "v"(b), "v"(c));
  return r;
}

// vectorized x-row stage: 4x dwordx4 + scalar tail, write f16x4 to LDS row
static __device__ __forceinline__ void stageXrow(const float* __restrict__ xr,
                                                 f16* __restrict__ dstRow, int s) {
  #pragma unroll
  for (int j = 0; j < 4; ++j) {
    float v[4];
    __builtin_memcpy(v, xr + 4 * s + 32 * j, 16);
    f16 t4[4];
    #pragma unroll
    for (int b = 0; b < 4; ++b) t4[b] = (f16)v[b];
    *reinterpret_cast<f16x4*>(&dstRow[4 * s + 32 * j]) = *reinterpret_cast<f16x4*>(t4);
  }
  if (s < 5) dstRow[128 + s] = (f16)xr[128 + s];
}

// ---------------- zk: z = h @ W. Dequant-at-stage in 2 K-phases (proven r18) ----------------
__global__ __launch_bounds__(512, 4)
void zk(char* __restrict__ h8, float* __restrict__ sce, const f16* __restrict__ wst) {
  __shared__ f16 Af[64 * 264];        // half-K (256) f16 A tile, row stride 264
  __shared__ f16 Bs[512 * 40];
  const int tid = threadIdx.x, lane = tid & 63, wid = tid >> 6;
  const int fr = lane & 15, fg = lane >> 4;
  const int wm = (wid >> 2) * 32, wn = (wid & 3) * 128;
  const int e0 = blockIdx.x * 64;
  const int sr = tid >> 3;
  const int sc8 = tid & 7;

  auto stageA = [&](int phase) {
    const int kb = phase * 256 + sc8 * 32;
    float sa = sce[(size_t)(e0 + sr) * 8 + (kb >> 6)];
    const f16 sh = (f16)sa;
    const f16 bh = (f16)(-1024.f * sa);
    f16x2 s2; s2[0] = sh; s2[1] = sh;
    f16x2 b2; b2[0] = bh; b2[1] = bh;
    const int4* src = reinterpret_cast<const int4*>(h8 + (size_t)(e0 + sr) * 512 + kb);
    f16* dst = &Af[sr * 264 + sc8 * 32];
    #pragma unroll
    for (int j = 0; j < 2; ++j) {
      int4 w = src[j];
      unsigned vv[4] = {(unsigned)w.x, (unsigned)w.y, (unsigned)w.z, (unsigned)w.w};
      #pragma unroll
      for (int q = 0; q < 2; ++q) {
        unsigned p0 = __builtin_amdgcn_perm(0x64646464u, vv[2*q],     0x05010400u);
        unsigned p1 = __builtin_amdgcn_perm(0x64646464u, vv[2*q],     0x05030402u);
        unsigned p2 = __builtin_amdgcn_perm(0x64646464u, vv[2*q + 1], 0x05010400u);
        unsigned p3 = __builtin_amdgcn_perm(0x64646464u, vv[2*q + 1], 0x05030402u);
        uint4 o;
        o.x = __builtin_bit_cast(unsigned, pkfma(__builtin_bit_cast(f16x2, p0), s2, b2));
        o.y = __builtin_bit_cast(unsigned, pkfma(__builtin_bit_cast(f16x2, p1), s2, b2));
        o.z = __builtin_bit_cast(unsigned, pkfma(__builtin_bit_cast(f16x2, p2), s2, b2));
        o.w = __builtin_bit_cast(unsigned, pkfma(__builtin_bit_cast(f16x2, p3), s2, b2));
        *reinterpret_cast<uint4*>(dst + j * 16 + q * 8) = o;
      }
    }
  };

  stageA(0);
  f32x4 acc[2][8] = {};
  for (int step = 0; step < 16; ++step) {
    if (step == 8) stageA(1);
    stageB512(wst + (size_t)step * 16384, Bs, tid);
    __syncthreads();
    const int ko = (step & 7) * 32;
    f16x8 af[2];
    #pragma unroll
    for (int mf = 0; mf < 2; ++mf)
      af[mf] = *reinterpret_cast<const f16x8*>(&Af[(wm + mf * 16 + fr) * 264 + ko + fg * 8]);
    #pragma unroll
    for (int nf = 0; nf < 8; ++nf) {
      f16x8 bf = *reinterpret_cast<const f16x8*>(&Bs[(wn + nf * 16 + fr) * 40 + fg * 8]);
      #pragma unroll
      for (int mf = 0; mf < 2; ++mf)
        acc[mf][nf] = __builtin_amdgcn_mfma_f32_16x16x32_f16(af[mf], bf, acc[mf][nf], 0, 0, 0);
    }
    __syncthreads();
  }
  float scA[2][4], scB[2][4];
  #pragma unroll
  for (int mf = 0; mf < 2; ++mf)
    #pragma unroll
    for (int i = 0; i < 4; ++i) {
      float mA = 0.f, mB = 0.f;
      #pragma unroll
      for (int nf = 0; nf < 4; ++nf) mA = fmaxf(mA, fabsf(acc[mf][nf][i]));
      #pragma unroll
      for (int nf = 4; nf < 8; ++nf) mB = fmaxf(mB, fabsf(acc[mf][nf][i]));
      #pragma unroll
      for (int d = 1; d < 16; d <<= 1) {
        mA = fmaxf(mA, __shfl_xor(mA, d));
        mB = fmaxf(mB, __shfl_xor(mB, d));
      }
      scA[mf][i] = (mA > 0.f) ? mA / 127.f : 1.f;
      scB[mf][i] = (mB > 0.f) ? mB / 127.f : 1.f;
      if (fr == 0) {
        int r = wm + mf * 16 + fg * 4 + i;
        sce[(size_t)(e0 + r) * 8 + (wn >> 6)]     = scA[mf][i];
        sce[(size_t)(e0 + r) * 8 + (wn >> 6) + 1] = scB[mf][i];
      }
    }
  char* q8 = (char*)&Bs[0];
  #pragma unroll
  for (int mf = 0; mf < 2; ++mf)
    #pragma unroll
    for (int nf = 0; nf < 8; ++nf) {
      int c = wn + nf * 16 + fr;
      #pragma unroll
      for (int i = 0; i < 4; ++i) {
        int r = wm + mf * 16 + fg * 4 + i;
        float s = (nf < 4) ? scA[mf][i] : scB[mf][i];
        int q = __float2int_rn(acc[mf][nf][i] / s);
        q8[r * 512 + c] = (char)min(127, max(-127, q));
      }
    }
  __syncthreads();
  { int4* dst = reinterpret_cast<int4*>(h8 + (size_t)e0 * 512);
    const int4* s4 = reinterpret_cast<const int4*>(q8);
    #pragma unroll
    for (int j = 0; j < 4; ++j) dst[tid * 4 + j] = s4[tid * 4 + j]; }
}

// ---------------- convup: half-width; B direct from L2, barrier-free 5-step loop ----------------
template<int MODE>
__global__ __launch_bounds__(512, 4)
void convup(const float* __restrict__ x, const float* __restrict__ ea,
            const int* __restrict__ row, const f16* __restrict__ wi,
            const float* __restrict__ bi, const float* __restrict__ bc,
            char* __restrict__ h8, float* __restrict__ sce,
            const char* __restrict__ msgq, const float* __restrict__ scm,
            int c0) {
  __shared__ f16 As[64 * 168];
  __shared__ char m8s[64 * 256];
  __shared__ float scmL[64 * 4];
  const int tid = threadIdx.x, lane = tid & 63, wid = tid >> 6;
  const int fr = lane & 15, fg = lane >> 4;
  const int wm = (wid >> 2) * 32, wn = (wid & 3) * 64;
  const int e0 = blockIdx.x * 64;

  { // stage A1 = [x[row]|ea] pad->160 (vectorized); msg tile for MODE 1
    int r = tid >> 3, s = tid & 7;
    int rid = row[e0 + r];
    stageXrow(x + (size_t)rid * 133, &As[r * 168], s);
    if (s < 7) {
      float2 e2 = *reinterpret_cast<const float2*>(ea + (size_t)(e0 + r) * 14 + 2 * s);
      As[r * 168 + 133 + 2 * s]     = (f16)e2.x;
      As[r * 168 + 133 + 2 * s + 1] = (f16)e2.y;
    }
    for (int k = 147 + s; k < 160; k += 8) As[r * 168 + k] = (f16)0.f;
    if (MODE == 1) {
      const int4* ms = reinterpret_cast<const int4*>(msgq + (size_t)(e0 + r) * 256 + s * 32);
      int4* md = reinterpret_cast<int4*>(m8s + r * 256 + s * 32);
      md[0] = ms[0]; md[1] = ms[1];
      if (s < 4) scmL[r * 4 + s] = scm[(size_t)(e0 + r) * 4 + s];
    }
  }
  __syncthreads();
  f32x4 acc[2][4] = {};
  #pragma unroll
  for (int step = 0; step < 5; ++step) {
    f16x8 bf[4];
    const f16* wsrc = wi + (size_t)step * 16384;
    #pragma unroll
    for (int nf = 0; nf < 4; ++nf)
      bf[nf] = *reinterpret_cast<const f16x8*>(
          &wsrc[(size_t)(c0 + wn + nf * 16 + fr) * 32 + fg * 8]);
    f16x8 af[2];
    #pragma unroll
    for (int mf = 0; mf < 2; ++mf)
      af[mf] = *reinterpret_cast<const f16x8*>(&As[(wm + mf * 16 + fr) * 168 + step * 32 + fg * 8]);
    #pragma unroll
    for (int nf = 0; nf < 4; ++nf)
      #pragma unroll
      for (int mf = 0; mf < 2; ++mf)
        acc[mf][nf] = __builtin_amdgcn_mfma_f32_16x16x32_f16(af[mf], bf[nf], acc[mf][nf], 0, 0, 0);
  }
  // epilogue: h0 = relu(gemm+bi); MODE1: h' = relu(h0 + bc + msg)
  #pragma unroll
  for (int nf = 0; nf < 4; ++nf) {
    int cl = wn + nf * 16 + fr;
    int cg = c0 + cl;
    float bi_ = bi[cg];
    float bc_ = (MODE == 1) ? bc[cg] : 0.f;
    #pragma unroll
    for (int mf = 0; mf < 2; ++mf)
      #pragma unroll
      for (int i = 0; i < 4; ++i) {
        int r = wm + mf * 16 + fg * 4 + i;
        float v = fmaxf(acc[mf][nf][i] + bi_, 0.f);
        if (MODE == 1) {
          float mv = (float)(char)m8s[r * 256 + cl] * scmL[r * 4 + (cl >> 6)];
          v = fmaxf(v + bc_ + mv, 0.f);
        }
        acc[mf][nf][i] = v;
      }
  }
  float sc_[2][4];
  #pragma unroll
  for (int mf = 0; mf < 2; ++mf)
    #pragma unroll
    for (int i = 0; i < 4; ++i) {
      float m = 0.f;
      #pragma unroll
      for (int nf = 0; nf < 4; ++nf) m = fmaxf(m, acc[mf][nf][i]);
      #pragma unroll
      for (int d = 1; d < 16; d <<= 1) m = fmaxf(m, __shfl_xor(m, d));
      sc_[mf][i] = (m > 0.f) ? m / 255.f : 1.f;
      if (fr == 0)
        sce[(size_t)(e0 + wm + mf * 16 + fg * 4 + i) * 8 + (c0 >> 6) + (wn >> 6)] = sc_[mf][i];
    }
  __syncthreads();   // all msg reads done before reusing m8s as bounce
  #pragma unroll
  for (int mf = 0; mf < 2; ++mf)
    #pragma unroll
    for (int nf = 0; nf < 4; ++nf) {
      int cl = wn + nf * 16 + fr;
      #pragma unroll
      for (int i = 0; i < 4; ++i) {
        int r = wm + mf * 16 + fg * 4 + i;
        int q = __float2int_rn(acc[mf][nf][i] / sc_[mf][i]);
        m8s[r * 256 + cl] = (char)(unsigned char)min(255, max(0, q));
      }
    }
  __syncthreads();
  { int r = tid >> 3, s = tid & 7;
    int4* dst = reinterpret_cast<int4*>(h8 + (size_t)(e0 + r) * 512 + c0 + s * 32);
    const int4* sp = reinterpret_cast<const int4*>(m8s + r * 256 + s * 32);
    dst[0] = sp[0]; dst[1] = sp[1]; }
}

// ---------------- e2n: B direct from L2, barrier-free GEMMs; vectorized gather ----------------
__global__ __launch_bounds__(512, 4)
void e2n(const float* __restrict__ x, const char* __restrict__ nb8,
         const float* __restrict__ scn, const f16* __restrict__ wex,
         const f16* __restrict__ wes, const float* __restrict__ be,
         const int* __restrict__ batch, float* __restrict__ pooled) {
  __shared__ f16 As[64 * 520];
  __shared__ int bat[64];
  const int tid = threadIdx.x, lane = tid & 63, wid = tid >> 6;
  const int fr = lane & 15, fg = lane >> 4;
  const int wm = (wid >> 2) * 32, wn = (wid & 3) * 128;
  const int n0 = blockIdx.x * 64;
  if (tid < 64) { int nn = n0 + tid; bat[tid] = (nn < NN) ? batch[nn] : 0; }
  { // x part, stride 168 (vectorized)
    int r = tid >> 3, s = tid & 7;
    int nid = min(n0 + r, NN - 1);
    stageXrow(x + (size_t)nid * 133, &As[r * 168], s);
    for (int k = 133 + s; k < 160; k += 8) As[r * 168 + k] = (f16)0.f;
  }
  __syncthreads();
  f32x4 acc[2][8] = {};
  for (int step = 0; step < 5; ++step) {
    f16x8 bf[8];
    loadBfrag(wex + (size_t)step * 16384, bf, wn, fr, fg);
    f16x8 af[2];
    #pragma unroll
    for (int mf = 0; mf < 2; ++mf)
      af[mf] = *reinterpret_cast<const f16x8*>(&As[(wm + mf * 16 + fr) * 168 + step * 32 + fg * 8]);
    #pragma unroll
    for (int nf = 0; nf < 8; ++nf)
      #pragma unroll
      for (int mf = 0; mf < 2; ++mf)
        acc[mf][nf] = __builtin_amdgcn_mfma_f32_16x16x32_f16(af[mf], bf[nf], acc[mf][nf], 0, 0, 0);
  }
  __syncthreads();
  { // re-stage As with dequantized s_node (u8 groupwise), stride 520
    int r = tid >> 3, s = tid & 7, kb = s * 64;
    int nid = min(n0 + r, NN - 1);
    float sc = scn[(size_t)nid * 8 + s];
    const int4* src = reinterpret_cast<const int4*>(nb8 + (size_t)nid * 512 + kb);
    #pragma unroll
    for (int j = 0; j < 4; ++j) {
      int4 w = src[j];
      unsigned vv[4] = {(unsigned)w.x, (unsigned)w.y, (unsigned)w.z, (unsigned)w.w};
      f16 tmp[16];
      #pragma unroll
      for (int q = 0; q < 4; ++q)
        #pragma unroll
        for (int b = 0; b < 4; ++b)
          tmp[q * 4 + b] = (f16)((float)((vv[q] >> (8 * b)) & 0xff) * sc);
      *reinterpret_cast<f16x8*>(&As[r * 520 + kb + j * 16])     = *reinterpret_cast<f16x8*>(&tmp[0]);
      *reinterpret_cast<f16x8*>(&As[r * 520 + kb + j * 16 + 8]) = *reinterpret_cast<f16x8*>(&tmp[8]);
    }
  }
  __syncthreads();
  for (int step = 0; step < 16; ++step) {
    f16x8 bf[8];
    loadBfrag(wes + (size_t)step * 16384, bf, wn, fr, fg);
    f16x8 af[2];
    #pragma unroll
    for (int mf = 0; mf < 2; ++mf)
      af[mf] = *reinterpret_cast<const f16x8*>(&As[(wm + mf * 16 + fr) * 520 + step * 32 + fg * 8]);
    #pragma unroll
    for (int nf = 0; nf < 8; ++nf)
      #pragma unroll
      for (int mf = 0; mf < 2; ++mf)
        acc[mf][nf] = __builtin_amdgcn_mfma_f32_16x16x32_f16(af[mf], bf[nf], acc[mf][nf], 0, 0, 0);
  }
  __syncthreads();
  // epilogue 1: hn -> As (f16 bounce, stride 520)
  #pragma unroll
  for (int nf = 0; nf < 8; ++nf) {
    int c = wn + nf * 16 + fr;
    float b_ = be[c];
    #pragma unroll
    for (int mf = 0; mf < 2; ++mf)
      #pragma unroll
      for (int i = 0; i < 4; ++i) {
        int rl = wm + mf * 16 + fg * 4 + i;
        As[rl * 520 + c] = (f16)fmaxf(acc[mf][nf][i] + b_, 0.f);
      }
  }
  __syncthreads();
  // epilogue 2: per-column segmented run-accumulate over sorted batch ids
  {
    const int c = tid;
    float s = 0.f;
    int pb = bat[0];
    #pragma unroll 1
    for (int r = 0; r < 64; ++r) {
      if (n0 + r >= NN) break;
      int b = bat[r];
      if (b != pb) {
        atomicAdd(&pooled[(size_t)pb * 512 + c], s);
        s = 0.f; pb = b;
      }
      s += (float)As[r * 520 + c];
    }
    atomicAdd(&pooled[(size_t)pb * 512 + c], s);
  }
}

// ---------------- ffn1 (fused): reads pooled f32 directly; computes final out ----------------
__global__ __launch_bounds__(512, 1)
void ffn1(const float* __restrict__ pooled, const f16* __restrict__ wf,
          const float* __restrict__ b1, const float* __restrict__ W2,
          const float* __restrict__ b2, float* __restrict__ out) {
  __shared__ f16 As[64 * 520];
  __shared__ f16 Bs[2][512 * 40];
  const int tid = threadIdx.x, lane = tid & 63, wid = tid >> 6;
  const int fr = lane & 15, fg = lane >> 4;
  const int wm = (wid >> 2) * 32, wn = (wid & 3) * 128;
  const int n0 = blockIdx.x * 64;
  { // stage pooled f32 -> f16 As (same values as old cast_ph + ph read)
    int r = tid >> 3, hs = (tid & 7) * 64;
    const float* ps = pooled + (size_t)(n0 + r) * 512 + hs;
    #pragma unroll
    for (int j = 0; j < 16; ++j) {
      float4 v = *reinterpret_cast<const float4*>(ps + j * 4);
      f16 t4[4];
      t4[0] = (f16)v.x; t4[1] = (f16)v.y; t4[2] = (f16)v.z; t4[3] = (f16)v.w;
      *reinterpret_cast<f16x4*>(&As[r * 520 + hs + j * 4]) = *reinterpret_cast<f16x4*>(t4);
    }
  }
  stageB512(wf, Bs[0], tid);
  __syncthreads();
  f32x4 acc[2][8] = {};
  for (int step = 0; step < 16; ++step) {
    const int cur = step & 1;
    f16x8 pf[4];
    if (step < 15) {
      const f16* wsrc = wf + (size_t)(step + 1) * 16384;
      #pragma unroll
      for (int j = 0; j < 4; ++j)
        pf[j] = *reinterpret_cast<const f16x8*>(&wsrc[(size_t)(tid * 4 + j) * 8]);
    }
    {
      f16x8 af[2];
      #pragma unroll
      for (int mf = 0; mf < 2; ++mf)
        af[mf] = *reinterpret_cast<const f16x8*>(&As[(wm + mf * 16 + fr) * 520 + step * 32 + fg * 8]);
      #pragma unroll
      for (int nf = 0; nf < 8; ++nf) {
        f16x8 bf = *reinterpret_cast<const f16x8*>(&Bs[cur][(wn + nf * 16 + fr) * 40 + fg * 8]);
        #pragma unroll
        for (int mf = 0; mf < 2; ++mf)
          acc[mf][nf] = __builtin_amdgcn_mfma_f32_16x16x32_f16(af[mf], bf, acc[mf][nf], 0, 0, 0);
      }
    }
    if (step < 15) {
      #pragma unroll
      for (int j = 0; j < 4; ++j) {
        int u = tid * 4 + j;
        *reinterpret_cast<f16x8*>(&Bs[cur ^ 1][(u >> 2) * 40 + (u & 3) * 8]) = pf[j];
      }
    }
    __syncthreads();
  }
  f16* q16 = As;  // bounce, stride 512
  #pragma unroll
  for (int nf = 0; nf < 8; ++nf) {
    int c = wn + nf * 16 + fr;
    float b_ = b1[c];
    #pragma unroll
    for (int mf = 0; mf < 2; ++mf)
      #pragma unroll
      for (int i = 0; i < 4; ++i) {
        int r = wm + mf * 16 + fg * 4 + i;
        q16[r * 512 + c] = (f16)fmaxf(acc[mf][nf][i] + b_, 0.f);
      }
  }
  __syncthreads();
  // fused final_out: out[n0+row] = q16[row] . W2 + b2  (8 partials/row, shfl reduce)
  {
    int r = tid >> 3, part = tid & 7;
    float s = 0.f;
    #pragma unroll
    for (int j = 0; j < 64; ++j)
      s += (float)q16[r * 512 + part * 64 + j] * W2[part * 64 + j];
    #pragma unroll
    for (int d = 1; d < 8; d <<= 1) s += __shfl_xor(s, d);
    if (part == 0) out[n0 + r] = s + b2[0];
  }
}

extern "C" void kernel_launch(void* const* d_in, const int* in_sizes, int n_in,
                              void* d_out, int out_size, void* d_ws, size_t ws_size,
                              hipStream_t stream) {
  const float* x      = (const float*)d_in[0];
  const float* ea     = (const float*)d_in[1];
  const int*   ei     = (const int*)d_in[2];
  const int*   batch  = (const int*)d_in[3];
  const float* W_init = (const float*)d_in[4];
  const float* b_init = (const float*)d_in[5];
  const float* W_conv = (const float*)d_in[6];
  const float* b_conv = (const float*)d_in[7];
  const float* W_e2n  = (const float*)d_in[8];
  const float* b_e2n  = (const float*)d_in[9];
  const float* W_ffn1 = (const float*)d_in[10];
  const float* b_ffn1 = (const float*)d_in[11];
  const float* W_ffn2 = (const float*)d_in[12];
  const float* b_ffn2 = (const float*)d_in[13];
  const int* row = ei;
  const int* col = ei + NE;
  float* out = (float*)d_out;

  if (ws_size < WS_NEEDED) {
    diag<<<(out_size + 255) / 256, 256, 0, stream>>>(out, out_size, (float)(ws_size >> 20));
    return;
  }

  char* ws = (char*)d_ws;
  char*  h8   = ws + O_H8;
  float* sce  = (float*)(ws + O_SCE);
  char*  msgq = ws + O_SHR;
  float* scm  = (float*)(ws + O_SHR + 40960000UL);
  char*  nb8  = ws + O_SHR;
  float* scn  = (float*)(ws + O_SHR + 51200000UL);
  f16*   wt   = (f16*)(ws + O_WT);
  int*   off  = (int*)(ws + O_OFF);
  int*   eid  = (int*)(ws + O_EID);
  float* pooled = (float*)(ws + V_POOL);
  int*   cnt  = (int*)(ws + V_CNT);
  int*   fill = (int*)(ws + V_FILL);
  int*   bsum = (int*)(ws + V_BSUM);

  f16* wi  = wt;
  f16* wc  = wi + 160 * 512;
  f16* wex = wc + 5 * 512 * 512;
  f16* wes = wex + 160 * 512;
  f16* wf1 = wes + 512 * 512;

  // all weight conversions in one launch (1,998,848 elems = 7808 x 256)
  transcast_all<<<7808, 256, 0, stream>>>(W_init, W_conv, W_e2n, W_ffn1, wt);

  zero16<<<(25000 + 255) / 256, 256, 0, stream>>>((ulong2*)cnt, 25000);
  countK<<<(NE + 255) / 256, 256, 0, stream>>>(col, cnt);
  scanA<<<98, 1024, 0, stream>>>(cnt, fill, bsum);
  scanB<<<1, 64, 0, stream>>>(bsum, 98);
  scanC<<<98, 1024, 0, stream>>>(cnt, fill, bsum, off);
  scatterK<<<(NE + 255) / 256, 256, 0, stream>>>(col, fill, eid);

  convup<0><<<2500, 512, 0, stream>>>(x, ea, row, wi, b_init, nullptr,
                                      h8, sce, nullptr, nullptr, 0);
  convup<0><<<2500, 512, 0, stream>>>(x, ea, row, wi, b_init, nullptr,
                                      h8, sce, nullptr, nullptr, 256);
  for (int l = 0; l < 5; ++l) {
    zk<<<2500, 512, 0, stream>>>(h8, sce, wc + (size_t)l * 262144);
    msgk<0><<<25000, 256, 0, stream>>>(h8, sce, off, eid, msgq, scm);
    convup<1><<<2500, 512, 0, stream>>>(x, ea, row, wi, b_init, b_conv + l * 512,
                                        h8, sce, msgq, scm, 0);
    msgk<256><<<25000, 256, 0, stream>>>(h8, sce, off, eid, msgq, scm);
    convup<1><<<2500, 512, 0, stream>>>(x, ea, row, wi, b_init, b_conv + l * 512,
                                        h8, sce, msgq, scm, 256);
  }
  tker<<<25000, 256, 0, stream>>>(h8, sce, off, eid, nb8, scn);
  zero16<<<(524288 + 255) / 256, 256, 0, stream>>>((ulong2*)pooled, 524288);
  e2n<<<1563, 512, 0, stream>>>(x, nb8, scn, wex, wes, b_e2n, batch, pooled);
  ffn1<<<64, 512, 0, stream>>>(pooled, wf1, b_ffn1, W_ffn2, b_ffn2, out);
}